// Round 9
// baseline (986.853 us; speedup 1.0000x reference)
//
#include <hip/hip_runtime.h>

#define D 64
#define NEG_SLOPE 0.01f
#define CB_SHIFT 10          // 1024 nodes per coarse bucket
#define CB_NODES 1024
#define MAXCB 128            // supports N <= 131072
#define CHUNK 8192           // edges per scatter block
#define SADJ_CAP 18432       // LDS adj stage (72 KB)

// ---------------------------------------------------------------------------
// Edge dtype detection, inline per wave: if all odd int32 words of the first
// 128 are zero, the buffer is int64 (little-endian high words).
// ---------------------------------------------------------------------------
__device__ __forceinline__ int detect64(const void* __restrict__ ei) {
    int lane = threadIdx.x & 63;
    int v = ((const int*)ei)[2 * lane + 1];
    return (__ballot(v != 0) == 0ULL) ? 1 : 0;
}

__device__ __forceinline__ int edge_at(const void* __restrict__ ei, long long idx, int is64) {
    if (is64) return (int)((const long long*)ei)[idx];
    return ((const int*)ei)[idx];
}

// ---------------------------------------------------------------------------
// Coarse histogram: per-block LDS hist of dst>>10, <=128 global atomics/block.
// ---------------------------------------------------------------------------
__global__ __launch_bounds__(256) void chist_kernel(
        const void* __restrict__ ei, long long E,
        int* __restrict__ ccount, int ncb) {
    __shared__ int hist[MAXCB];
    int t = threadIdx.x;
    if (t < MAXCB) hist[t] = 0;
    int is64 = detect64(ei);
    __syncthreads();
    long long tid = (long long)blockIdx.x * blockDim.x + t;
    long long nt = (long long)gridDim.x * blockDim.x;
    for (long long e = tid; e < E; e += nt) {
        int d = edge_at(ei, E + e, is64);
        atomicAdd(&hist[d >> CB_SHIFT], 1);
    }
    __syncthreads();
    if (t < ncb && hist[t]) atomicAdd(&ccount[t], hist[t]);
}

// parallel exclusive scan of <=128 bucket counts (one block, 128 threads)
__global__ void cscan_kernel(const int* __restrict__ ccount, int* __restrict__ cbase,
                             int* __restrict__ ccur, int* __restrict__ rowptr,
                             int ncb, int N, int E) {
    __shared__ int wsum[2];
    int t = threadIdx.x;           // 128 threads
    int v = (t < ncb) ? ccount[t] : 0;
    int lane = t & 63, w = t >> 6;
    int inc = v;
    for (int off = 1; off < 64; off <<= 1) {
        int u = __shfl_up(inc, off, 64);
        if (lane >= off) inc += u;
    }
    if (lane == 63) wsum[w] = inc;
    __syncthreads();
    int ex = inc - v + ((w == 1) ? wsum[0] : 0);
    if (t < ncb) { cbase[t] = ex; ccur[t] = ex; }
    if (t == 0) { cbase[ncb] = wsum[0] + wsum[1]; rowptr[N] = E; }
}

// ---------------------------------------------------------------------------
// Coarse scatter: LDS-sort an 8192-edge chunk into coarse-bucket order,
// reserve one contiguous global run per (block,bucket), flush packed
// (src<<10 | dstLocal) words in coalesced runs.
// ---------------------------------------------------------------------------
__global__ __launch_bounds__(256) void scatter_kernel(
        const void* __restrict__ ei, long long E,
        int* __restrict__ ccur, unsigned* __restrict__ ebuf, int ncb) {
    __shared__ int hist[MAXCB];
    __shared__ int lofs[MAXCB];
    __shared__ int gbase[MAXCB];
    __shared__ int cur[MAXCB];
    __shared__ unsigned spk[CHUNK];
    __shared__ unsigned char sbk[CHUNK];
    int t = threadIdx.x;
    if (t < MAXCB) hist[t] = 0;
    int is64 = detect64(ei);
    __syncthreads();
    long long start = (long long)blockIdx.x * CHUNK;
    int ccnt = (int)min((long long)CHUNK, E - start);

    for (int i = t; i < ccnt; i += 256) {
        int d = edge_at(ei, E + start + i, is64);
        atomicAdd(&hist[d >> CB_SHIFT], 1);
    }
    __syncthreads();
    if (t == 0) {
        int run = 0;
        for (int b = 0; b < ncb; ++b) { lofs[b] = run; run += hist[b]; }
    }
    if (t < ncb && hist[t]) gbase[t] = atomicAdd(&ccur[t], hist[t]);
    __syncthreads();
    if (t < ncb) cur[t] = lofs[t];
    __syncthreads();

    for (int i = t; i < ccnt; i += 256) {
        int s = edge_at(ei, start + i, is64);
        int d = edge_at(ei, E + start + i, is64);
        int b = d >> CB_SHIFT;
        int slot = atomicAdd(&cur[b], 1);
        spk[slot] = ((unsigned)s << CB_SHIFT) | (unsigned)(d & (CB_NODES - 1));
        sbk[slot] = (unsigned char)b;
    }
    __syncthreads();

    for (int i = t; i < ccnt; i += 256) {
        int b = sbk[i];
        ebuf[gbase[b] + (i - lofs[b])] = spk[i];
    }
}

// ---------------------------------------------------------------------------
// Fine fill: one block per coarse bucket; per-node count + scan -> rowptr;
// LDS ticket placement; coalesced flush. Scattered writes stay in LDS.
// ---------------------------------------------------------------------------
__global__ __launch_bounds__(256) void finefill_kernel(
        const unsigned* __restrict__ ebuf, const int* __restrict__ cbase,
        int* __restrict__ rowptr, int* __restrict__ adj, int N) {
    __shared__ int cnt[CB_NODES];
    __shared__ int cur[CB_NODES];
    __shared__ int wpart[4];
    __shared__ int sAdj[SADJ_CAP];
    int t = threadIdx.x;
    int b = blockIdx.x;
    int e0 = cbase[b], e1 = cbase[b + 1];
    int len = e1 - e0;
    int nb = b << CB_SHIFT;

    for (int i = t; i < CB_NODES; i += 256) cnt[i] = 0;
    __syncthreads();
    for (int i = t; i < len; i += 256) {
        unsigned p = ebuf[e0 + i];
        atomicAdd(&cnt[p & (CB_NODES - 1)], 1);
    }
    __syncthreads();

    int c0 = cnt[4 * t], c1 = cnt[4 * t + 1], c2 = cnt[4 * t + 2], c3 = cnt[4 * t + 3];
    int s = c0 + c1 + c2 + c3;
    int lane = t & 63, wv = t >> 6;
    int inc = s;
    for (int off = 1; off < 64; off <<= 1) {
        int u = __shfl_up(inc, off, 64);
        if (lane >= off) inc += u;
    }
    if (lane == 63) wpart[wv] = inc;
    __syncthreads();
    int wof = 0;
    for (int w = 0; w < wv; ++w) wof += wpart[w];
    int ex = wof + inc - s;
    int o0 = ex, o1 = ex + c0, o2 = o1 + c1, o3 = o2 + c2;
    cur[4 * t] = o0; cur[4 * t + 1] = o1; cur[4 * t + 2] = o2; cur[4 * t + 3] = o3;
    {
        int g = nb + 4 * t;
        if (g < N)     rowptr[g]     = e0 + o0;
        if (g + 1 < N) rowptr[g + 1] = e0 + o1;
        if (g + 2 < N) rowptr[g + 2] = e0 + o2;
        if (g + 3 < N) rowptr[g + 3] = e0 + o3;
    }
    __syncthreads();

    int big = (len > SADJ_CAP);
    for (int i = t; i < len; i += 256) {
        unsigned p = ebuf[e0 + i];
        int dl = (int)(p & (CB_NODES - 1));
        int src = (int)(p >> CB_SHIFT);
        int pos = atomicAdd(&cur[dl], 1);
        if (big) adj[e0 + pos] = src;
        else     sAdj[pos] = src;
    }
    __syncthreads();
    if (!big) {
        for (int i = t; i < len; i += 256) adj[e0 + i] = sAdj[i];
    }
}

// ---------------------------------------------------------------------------
// Gather+mean: wave per node (grid-stride). 16 lanes per neighbor row
// (float4/lane); unroll 4 -> 16 rows in flight. No LDS, VGPR 16 -> max
// occupancy. UNCHANGED (measured 61 us; FETCH 178 MB = structural per-XCD
// floor for a random graph; LLC-bound at ~3.4 TB/s).
// ---------------------------------------------------------------------------
__global__ __launch_bounds__(256) void agg_kernel(
        const float* __restrict__ hin, const int* __restrict__ rowptr,
        const int* __restrict__ adj, float* __restrict__ mout, int N) {
    int lane = threadIdx.x & 63;
    int sub = lane & 15;      // float4 slot within row
    int grp = lane >> 4;      // which of 4 concurrent rows
    int wid = blockIdx.x * (blockDim.x >> 6) + (threadIdx.x >> 6);
    int nw = gridDim.x * (blockDim.x >> 6);

    for (int i = wid; i < N; i += nw) {
        int b0 = rowptr[i], b1 = rowptr[i + 1];
        float ax = 0.f, ay = 0.f, az = 0.f, aw = 0.f;
        for (int base = b0; base < b1; base += 64) {
            int idx = base + lane;
            int sl = (idx < b1) ? adj[idx] : 0;   // coalesced adj chunk
            int cnt = min(64, b1 - base);
            int nq = (cnt + 3) >> 2;
#pragma unroll 4
            for (int t = 0; t < nq; ++t) {
                int j = (t << 2) + grp;
                int s = __shfl(sl, j, 64);
                if (j < cnt) {
                    const float4 v = *(const float4*)(hin + (size_t)s * D + (sub << 2));
                    ax += v.x; ay += v.y; az += v.z; aw += v.w;
                }
            }
        }
        ax += __shfl_xor(ax, 16, 64); ay += __shfl_xor(ay, 16, 64);
        az += __shfl_xor(az, 16, 64); aw += __shfl_xor(aw, 16, 64);
        ax += __shfl_xor(ax, 32, 64); ay += __shfl_xor(ay, 32, 64);
        az += __shfl_xor(az, 32, 64); aw += __shfl_xor(aw, 32, 64);
        if (grp == 0) {
            float inv = 1.0f / fmaxf((float)(b1 - b0), 1.0f);
            float4 r = make_float4(ax * inv, ay * inv, az * inv, aw * inv);
            *(float4*)(mout + (size_t)i * D + (sub << 2)) = r;
        }
    }
}

// ---------------------------------------------------------------------------
// Transform v3: thread-per-node, NO LDS, NO barriers. acc[64] in VGPRs;
// W accessed with wave-uniform indices -> compiler emits s_load (SGPR
// operands, scalar pipe; W is 16 KB, scalar-cache resident). Each thread
// streams its mean row, then its hin row, as float4; 8192 v_fmac total.
// In-place over io (thread owns its row). final_flag: in-thread head dot.
// ---------------------------------------------------------------------------
__global__ __launch_bounds__(256) void transform_kernel(
        float* __restrict__ io, const float* __restrict__ hin,
        const float* __restrict__ Wl, const float* __restrict__ bl,
        const float* __restrict__ Wr,
        const float* __restrict__ Wout, const float* __restrict__ bout,
        float* __restrict__ out, int N, int final_flag) {
    int i = blockIdx.x * blockDim.x + threadIdx.x;
    if (i >= N) return;

    float acc[D];
#pragma unroll
    for (int c = 0; c < D; ++c) acc[c] = bl[c];   // uniform -> s_load

    const float* mrow = io + (size_t)i * D;
#pragma unroll 4
    for (int k0 = 0; k0 < 16; ++k0) {
        const float4 m4 = *(const float4*)(mrow + k0 * 4);
#pragma unroll
        for (int c = 0; c < D; ++c) {
            const float* wr = Wl + c * D + k0 * 4;   // uniform -> s_load
            acc[c] += m4.x * wr[0] + m4.y * wr[1] + m4.z * wr[2] + m4.w * wr[3];
        }
    }

    const float* xrow = hin + (size_t)i * D;
#pragma unroll 4
    for (int k0 = 0; k0 < 16; ++k0) {
        const float4 x4 = *(const float4*)(xrow + k0 * 4);
#pragma unroll
        for (int c = 0; c < D; ++c) {
            const float* wr = Wr + c * D + k0 * 4;   // uniform -> s_load
            acc[c] += x4.x * wr[0] + x4.y * wr[1] + x4.z * wr[2] + x4.w * wr[3];
        }
    }

    if (!final_flag) {
        float* orow = io + (size_t)i * D;
#pragma unroll
        for (int c0 = 0; c0 < 16; ++c0) {
            float4 r;
            float y0 = acc[4 * c0 + 0]; r.x = (y0 >= 0.f) ? y0 : NEG_SLOPE * y0;
            float y1 = acc[4 * c0 + 1]; r.y = (y1 >= 0.f) ? y1 : NEG_SLOPE * y1;
            float y2 = acc[4 * c0 + 2]; r.z = (y2 >= 0.f) ? y2 : NEG_SLOPE * y2;
            float y3 = acc[4 * c0 + 3]; r.w = (y3 >= 0.f) ? y3 : NEG_SLOPE * y3;
            *(float4*)(orow + 4 * c0) = r;
        }
    } else {
        float p = bout[0];
#pragma unroll
        for (int c = 0; c < D; ++c) {
            float y = acc[c];
            y = (y >= 0.f) ? y : NEG_SLOPE * y;
            p += y * Wout[c];                        // uniform -> s_load
        }
        out[i] = p;
    }
}

extern "C" void kernel_launch(void* const* d_in, const int* in_sizes, int n_in,
                              void* d_out, int out_size, void* d_ws, size_t ws_size,
                              hipStream_t stream) {
    const float* x    = (const float*)d_in[0];
    const void*  ei   = d_in[1];
    const float* Wl1  = (const float*)d_in[2];
    const float* bl1  = (const float*)d_in[3];
    const float* Wr1  = (const float*)d_in[4];
    const float* Wl2  = (const float*)d_in[5];
    const float* bl2  = (const float*)d_in[6];
    const float* Wr2  = (const float*)d_in[7];
    const float* Wl3  = (const float*)d_in[8];
    const float* bl3  = (const float*)d_in[9];
    const float* Wr3  = (const float*)d_in[10];
    const float* Wout = (const float*)d_in[11];
    const float* bout = (const float*)d_in[12];
    float* out = (float*)d_out;

    int       N = in_sizes[0] / D;
    long long E = (long long)in_sizes[1] / 2;
    int ncb = (N + CB_NODES - 1) >> CB_SHIFT;   // <= MAXCB for N <= 131072

    // workspace layout
    char* ws = (char*)d_ws;
    size_t off = 256;
    int* ccount = (int*)(ws + off); off += 512;
    int* cbase  = (int*)(ws + off); off += 1024;
    int* ccur   = (int*)(ws + off); off += 512;
    int* rowptr = (int*)(ws + off); off += (((size_t)(N + 1) * 4 + 255) / 256) * 256;
    int* adj    = (int*)(ws + off); off += (((size_t)E * 4 + 255) / 256) * 256;
    float* bufA = (float*)(ws + off); off += (size_t)N * D * 4;
    float* bufB = (float*)(ws + off);
    unsigned* ebuf = (unsigned*)bufB;  // consumed by finefill before bufB's first write

    // ---- CSR build via two-level counting sort (once; graph layer-invariant) ----
    hipMemsetAsync(ccount, 0, 512, stream);
    chist_kernel<<<256, 256, 0, stream>>>(ei, E, ccount, ncb);
    cscan_kernel<<<1, 128, 0, stream>>>(ccount, cbase, ccur, rowptr, ncb, N, (int)E);
    int sgrid = (int)((E + CHUNK - 1) / CHUNK);
    scatter_kernel<<<sgrid, 256, 0, stream>>>(ei, E, ccur, ebuf, ncb);
    finefill_kernel<<<ncb, 256, 0, stream>>>(ebuf, cbase, rowptr, adj, N);

    int tgrid = (N + 255) / 256;

    // ---- layer 1: x -> bufA ----
    agg_kernel<<<4096, 256, 0, stream>>>(x, rowptr, adj, bufA, N);
    transform_kernel<<<tgrid, 256, 0, stream>>>(bufA, x, Wl1, bl1, Wr1,
                                                Wout, bout, out, N, 0);
    // ---- layer 2: bufA -> bufB ----
    agg_kernel<<<4096, 256, 0, stream>>>(bufA, rowptr, adj, bufB, N);
    transform_kernel<<<tgrid, 256, 0, stream>>>(bufB, bufA, Wl2, bl2, Wr2,
                                                Wout, bout, out, N, 0);
    // ---- layer 3 + fused head: bufB -> out ----
    agg_kernel<<<4096, 256, 0, stream>>>(bufB, rowptr, adj, bufA, N);
    transform_kernel<<<tgrid, 256, 0, stream>>>(bufA, bufB, Wl3, bl3, Wr3,
                                                Wout, bout, out, N, 1);
}

// Round 10
// 458.191 us; speedup vs baseline: 2.1538x; 2.1538x over previous
//
#include <hip/hip_runtime.h>

#define D 64
#define NEG_SLOPE 0.01f
#define CB_SHIFT 10          // 1024 nodes per coarse bucket
#define CB_NODES 1024
#define MAXCB 128            // supports N <= 131072
#define CHUNK 8192           // edges per scatter block
#define SADJ_CAP 18432       // LDS adj stage (72 KB)
#define SA_STRIDE 132        // 128 nodes + 4 pad (k-major tile)  [R5-proven]
#define SW2_STRIDE 132       // 128 ch + 4 pad (k-major, Wl|Wr concat)

// ---------------------------------------------------------------------------
// Edge dtype detection, inline per wave: if all odd int32 words of the first
// 128 are zero, the buffer is int64 (little-endian high words).
// ---------------------------------------------------------------------------
__device__ __forceinline__ int detect64(const void* __restrict__ ei) {
    int lane = threadIdx.x & 63;
    int v = ((const int*)ei)[2 * lane + 1];
    return (__ballot(v != 0) == 0ULL) ? 1 : 0;
}

__device__ __forceinline__ int edge_at(const void* __restrict__ ei, long long idx, int is64) {
    if (is64) return (int)((const long long*)ei)[idx];
    return ((const int*)ei)[idx];
}

// ---------------------------------------------------------------------------
// Coarse histogram: per-block LDS hist of dst>>10, <=128 global atomics/block.
// ---------------------------------------------------------------------------
__global__ __launch_bounds__(256) void chist_kernel(
        const void* __restrict__ ei, long long E,
        int* __restrict__ ccount, int ncb) {
    __shared__ int hist[MAXCB];
    int t = threadIdx.x;
    if (t < MAXCB) hist[t] = 0;
    int is64 = detect64(ei);
    __syncthreads();
    long long tid = (long long)blockIdx.x * blockDim.x + t;
    long long nt = (long long)gridDim.x * blockDim.x;
    for (long long e = tid; e < E; e += nt) {
        int d = edge_at(ei, E + e, is64);
        atomicAdd(&hist[d >> CB_SHIFT], 1);
    }
    __syncthreads();
    if (t < ncb && hist[t]) atomicAdd(&ccount[t], hist[t]);
}

// parallel exclusive scan of <=128 bucket counts (one block, 128 threads)
__global__ void cscan_kernel(const int* __restrict__ ccount, int* __restrict__ cbase,
                             int* __restrict__ ccur, int* __restrict__ rowptr,
                             int ncb, int N, int E) {
    __shared__ int wsum[2];
    int t = threadIdx.x;           // 128 threads
    int v = (t < ncb) ? ccount[t] : 0;
    int lane = t & 63, w = t >> 6;
    int inc = v;
    for (int off = 1; off < 64; off <<= 1) {
        int u = __shfl_up(inc, off, 64);
        if (lane >= off) inc += u;
    }
    if (lane == 63) wsum[w] = inc;
    __syncthreads();
    int ex = inc - v + ((w == 1) ? wsum[0] : 0);
    if (t < ncb) { cbase[t] = ex; ccur[t] = ex; }
    if (t == 0) { cbase[ncb] = wsum[0] + wsum[1]; rowptr[N] = E; }
}

// ---------------------------------------------------------------------------
// Coarse scatter: LDS-sort an 8192-edge chunk into coarse-bucket order,
// reserve one contiguous global run per (block,bucket), flush packed
// (src<<10 | dstLocal) words in coalesced runs.
// ---------------------------------------------------------------------------
__global__ __launch_bounds__(256) void scatter_kernel(
        const void* __restrict__ ei, long long E,
        int* __restrict__ ccur, unsigned* __restrict__ ebuf, int ncb) {
    __shared__ int hist[MAXCB];
    __shared__ int lofs[MAXCB];
    __shared__ int gbase[MAXCB];
    __shared__ int cur[MAXCB];
    __shared__ unsigned spk[CHUNK];
    __shared__ unsigned char sbk[CHUNK];
    int t = threadIdx.x;
    if (t < MAXCB) hist[t] = 0;
    int is64 = detect64(ei);
    __syncthreads();
    long long start = (long long)blockIdx.x * CHUNK;
    int ccnt = (int)min((long long)CHUNK, E - start);

    for (int i = t; i < ccnt; i += 256) {
        int d = edge_at(ei, E + start + i, is64);
        atomicAdd(&hist[d >> CB_SHIFT], 1);
    }
    __syncthreads();
    if (t == 0) {
        int run = 0;
        for (int b = 0; b < ncb; ++b) { lofs[b] = run; run += hist[b]; }
    }
    if (t < ncb && hist[t]) gbase[t] = atomicAdd(&ccur[t], hist[t]);
    __syncthreads();
    if (t < ncb) cur[t] = lofs[t];
    __syncthreads();

    for (int i = t; i < ccnt; i += 256) {
        int s = edge_at(ei, start + i, is64);
        int d = edge_at(ei, E + start + i, is64);
        int b = d >> CB_SHIFT;
        int slot = atomicAdd(&cur[b], 1);
        spk[slot] = ((unsigned)s << CB_SHIFT) | (unsigned)(d & (CB_NODES - 1));
        sbk[slot] = (unsigned char)b;
    }
    __syncthreads();

    for (int i = t; i < ccnt; i += 256) {
        int b = sbk[i];
        ebuf[gbase[b] + (i - lofs[b])] = spk[i];
    }
}

// ---------------------------------------------------------------------------
// Fine fill: one block per coarse bucket; per-node count + scan -> rowptr;
// LDS ticket placement; coalesced flush. Scattered writes stay in LDS.
// ---------------------------------------------------------------------------
__global__ __launch_bounds__(256) void finefill_kernel(
        const unsigned* __restrict__ ebuf, const int* __restrict__ cbase,
        int* __restrict__ rowptr, int* __restrict__ adj, int N) {
    __shared__ int cnt[CB_NODES];
    __shared__ int cur[CB_NODES];
    __shared__ int wpart[4];
    __shared__ int sAdj[SADJ_CAP];
    int t = threadIdx.x;
    int b = blockIdx.x;
    int e0 = cbase[b], e1 = cbase[b + 1];
    int len = e1 - e0;
    int nb = b << CB_SHIFT;

    for (int i = t; i < CB_NODES; i += 256) cnt[i] = 0;
    __syncthreads();
    for (int i = t; i < len; i += 256) {
        unsigned p = ebuf[e0 + i];
        atomicAdd(&cnt[p & (CB_NODES - 1)], 1);
    }
    __syncthreads();

    int c0 = cnt[4 * t], c1 = cnt[4 * t + 1], c2 = cnt[4 * t + 2], c3 = cnt[4 * t + 3];
    int s = c0 + c1 + c2 + c3;
    int lane = t & 63, wv = t >> 6;
    int inc = s;
    for (int off = 1; off < 64; off <<= 1) {
        int u = __shfl_up(inc, off, 64);
        if (lane >= off) inc += u;
    }
    if (lane == 63) wpart[wv] = inc;
    __syncthreads();
    int wof = 0;
    for (int w = 0; w < wv; ++w) wof += wpart[w];
    int ex = wof + inc - s;
    int o0 = ex, o1 = ex + c0, o2 = o1 + c1, o3 = o2 + c2;
    cur[4 * t] = o0; cur[4 * t + 1] = o1; cur[4 * t + 2] = o2; cur[4 * t + 3] = o3;
    {
        int g = nb + 4 * t;
        if (g < N)     rowptr[g]     = e0 + o0;
        if (g + 1 < N) rowptr[g + 1] = e0 + o1;
        if (g + 2 < N) rowptr[g + 2] = e0 + o2;
        if (g + 3 < N) rowptr[g + 3] = e0 + o3;
    }
    __syncthreads();

    int big = (len > SADJ_CAP);
    for (int i = t; i < len; i += 256) {
        unsigned p = ebuf[e0 + i];
        int dl = (int)(p & (CB_NODES - 1));
        int src = (int)(p >> CB_SHIFT);
        int pos = atomicAdd(&cur[dl], 1);
        if (big) adj[e0 + pos] = src;
        else     sAdj[pos] = src;
    }
    __syncthreads();
    if (!big) {
        for (int i = t; i < len; i += 256) adj[e0 + i] = sAdj[i];
    }
}

// ---------------------------------------------------------------------------
// R5-proven k-major staging: 128-node x 64-k tile TRANSPOSED into LDS.
// Reads ONLY this block's own rows (clamp targets N-1, last block's row).
// ---------------------------------------------------------------------------
__device__ __forceinline__ void stage_tile_T(float* __restrict__ sA,
        const float* __restrict__ g, int node_base, int N, int t) {
    int nq = t >> 4;   // 0..15
    int kq = t & 15;   // 0..15
#pragma unroll
    for (int p = 0; p < 8; ++p) {
        int node = p * 16 + nq;
        int gn = node_base + node;
        if (gn >= N) gn = N - 1;   // pad rows: garbage ok, stores masked
        const float4 v = *(const float4*)(g + (size_t)gn * D + (kq << 2));
        sA[(kq * 4 + 0) * SA_STRIDE + node] = v.x;
        sA[(kq * 4 + 1) * SA_STRIDE + node] = v.y;
        sA[(kq * 4 + 2) * SA_STRIDE + node] = v.z;
        sA[(kq * 4 + 3) * SA_STRIDE + node] = v.w;
    }
}

// ---------------------------------------------------------------------------
// gemm_kernel: per layer, ONE pass over h computes BOTH
//   P = h @ Wl^T          (written to P buffer)
//   R = h @ Wr^T + bl     (written IN PLACE over h: block owns its rows)
// Exploits SAGE linearity: mean(x_j) @ Wl^T == mean(x_j @ Wl^T), so the
// gather can run on P afterwards. Single staged A-tile, W in LDS k-major
// (Wl cols 0-63, Wr cols 64-127), one barrier pair, thread tile 8n x 8c.
// LDS 67.6 KB -> 2 blocks/CU; acc[8][8]=64 VGPR (2 waves/SIMD: <=256 ok).
// ---------------------------------------------------------------------------
__global__ __launch_bounds__(256) void gemm_kernel(
        const float* __restrict__ h, const float* __restrict__ Wl,
        const float* __restrict__ Wr, const float* __restrict__ bl,
        float* __restrict__ P, float* __restrict__ R, int N) {
    __shared__ float sA[64 * SA_STRIDE];
    __shared__ float sW[64 * SW2_STRIDE];
    int t = threadIdx.x;
    int node_base = blockIdx.x * 128;

    stage_tile_T(sA, h, node_base, N, t);
    {   // stage Wl -> cols 0..63, Wr -> cols 64..127 (k-major)
        int cq = t >> 4, kq = t & 15;
#pragma unroll
        for (int p = 0; p < 4; ++p) {
            int c = p * 16 + cq;
            const float4 vl = *(const float4*)(Wl + c * D + (kq << 2));
            sW[(kq * 4 + 0) * SW2_STRIDE + c] = vl.x;
            sW[(kq * 4 + 1) * SW2_STRIDE + c] = vl.y;
            sW[(kq * 4 + 2) * SW2_STRIDE + c] = vl.z;
            sW[(kq * 4 + 3) * SW2_STRIDE + c] = vl.w;
            const float4 vr = *(const float4*)(Wr + c * D + (kq << 2));
            sW[(kq * 4 + 0) * SW2_STRIDE + 64 + c] = vr.x;
            sW[(kq * 4 + 1) * SW2_STRIDE + 64 + c] = vr.y;
            sW[(kq * 4 + 2) * SW2_STRIDE + 64 + c] = vr.z;
            sW[(kq * 4 + 3) * SW2_STRIDE + 64 + c] = vr.w;
        }
    }
    __syncthreads();

    int ng = t >> 4;   // node group: 8 nodes (ng*8..)
    int cg = t & 15;   // ch group: 8 ch (cg*8..); cg<8 -> P, cg>=8 -> R
    float acc[8][8];
#pragma unroll
    for (int i = 0; i < 8; ++i)
#pragma unroll
        for (int j = 0; j < 8; ++j) acc[i][j] = 0.f;

#pragma unroll 2
    for (int k = 0; k < 64; ++k) {
        const float4 qa0 = *(const float4*)&sA[k * SA_STRIDE + ng * 8];
        const float4 qa1 = *(const float4*)&sA[k * SA_STRIDE + ng * 8 + 4];
        const float4 qw0 = *(const float4*)&sW[k * SW2_STRIDE + cg * 8];
        const float4 qw1 = *(const float4*)&sW[k * SW2_STRIDE + cg * 8 + 4];
        float av[8] = {qa0.x, qa0.y, qa0.z, qa0.w, qa1.x, qa1.y, qa1.z, qa1.w};
        float wv[8] = {qw0.x, qw0.y, qw0.z, qw0.w, qw1.x, qw1.y, qw1.z, qw1.w};
#pragma unroll
        for (int i = 0; i < 8; ++i)
#pragma unroll
            for (int j = 0; j < 8; ++j)
                acc[i][j] = __builtin_fmaf(av[i], wv[j], acc[i][j]);
    }

    // epilogue: cg<8 writes P channels cg*8..+7; cg>=8 writes R=(acc+bl)
    if (cg < 8) {
        int c0 = cg * 8;
#pragma unroll
        for (int i = 0; i < 8; ++i) {
            int gn = node_base + ng * 8 + i;
            if (gn < N) {
                *(float4*)(P + (size_t)gn * D + c0) =
                    make_float4(acc[i][0], acc[i][1], acc[i][2], acc[i][3]);
                *(float4*)(P + (size_t)gn * D + c0 + 4) =
                    make_float4(acc[i][4], acc[i][5], acc[i][6], acc[i][7]);
            }
        }
    } else {
        int c0 = (cg - 8) * 8;
        const float4 b0 = *(const float4*)&bl[c0];
        const float4 b1 = *(const float4*)&bl[c0 + 4];
#pragma unroll
        for (int i = 0; i < 8; ++i) {
            int gn = node_base + ng * 8 + i;
            if (gn < N) {
                *(float4*)(R + (size_t)gn * D + c0) =
                    make_float4(acc[i][0] + b0.x, acc[i][1] + b0.y,
                                acc[i][2] + b0.z, acc[i][3] + b0.w);
                *(float4*)(R + (size_t)gn * D + c0 + 4) =
                    make_float4(acc[i][4] + b1.x, acc[i][5] + b1.y,
                                acc[i][6] + b1.z, acc[i][7] + b1.w);
            }
        }
    }
}

// ---------------------------------------------------------------------------
// agg2: proven gather structure over P; epilogue h_next = leaky(meanP + R)
// written IN PLACE over R (wave owns row). final_flag: fused head
// out[i] = bout + Wout . leaky(meanP + R)  (16-lane dot + shfl reduce).
// ---------------------------------------------------------------------------
__global__ __launch_bounds__(256) void agg2_kernel(
        const float* __restrict__ P, const float* __restrict__ R,
        const int* __restrict__ rowptr, const int* __restrict__ adj,
        const float* __restrict__ Wout, const float* __restrict__ bout,
        float* __restrict__ hout, float* __restrict__ out,
        int N, int final_flag) {
    int lane = threadIdx.x & 63;
    int sub = lane & 15;      // float4 slot within row
    int grp = lane >> 4;      // which of 4 concurrent rows
    int wid = blockIdx.x * (blockDim.x >> 6) + (threadIdx.x >> 6);
    int nw = gridDim.x * (blockDim.x >> 6);

    for (int i = wid; i < N; i += nw) {
        int b0 = rowptr[i], b1 = rowptr[i + 1];
        float ax = 0.f, ay = 0.f, az = 0.f, aw = 0.f;
        for (int base = b0; base < b1; base += 64) {
            int idx = base + lane;
            int sl = (idx < b1) ? adj[idx] : 0;   // coalesced adj chunk
            int cnt = min(64, b1 - base);
            int nq = (cnt + 3) >> 2;
#pragma unroll 4
            for (int t = 0; t < nq; ++t) {
                int j = (t << 2) + grp;
                int s = __shfl(sl, j, 64);
                if (j < cnt) {
                    const float4 v = *(const float4*)(P + (size_t)s * D + (sub << 2));
                    ax += v.x; ay += v.y; az += v.z; aw += v.w;
                }
            }
        }
        ax += __shfl_xor(ax, 16, 64); ay += __shfl_xor(ay, 16, 64);
        az += __shfl_xor(az, 16, 64); aw += __shfl_xor(aw, 16, 64);
        ax += __shfl_xor(ax, 32, 64); ay += __shfl_xor(ay, 32, 64);
        az += __shfl_xor(az, 32, 64); aw += __shfl_xor(aw, 32, 64);
        if (grp == 0) {
            float inv = 1.0f / fmaxf((float)(b1 - b0), 1.0f);
            const float4 r4 = *(const float4*)(R + (size_t)i * D + (sub << 2));
            float y0 = ax * inv + r4.x; y0 = (y0 >= 0.f) ? y0 : NEG_SLOPE * y0;
            float y1 = ay * inv + r4.y; y1 = (y1 >= 0.f) ? y1 : NEG_SLOPE * y1;
            float y2 = az * inv + r4.z; y2 = (y2 >= 0.f) ? y2 : NEG_SLOPE * y2;
            float y3 = aw * inv + r4.w; y3 = (y3 >= 0.f) ? y3 : NEG_SLOPE * y3;
            if (!final_flag) {
                *(float4*)(hout + (size_t)i * D + (sub << 2)) =
                    make_float4(y0, y1, y2, y3);
            } else {
                const float4 w4 = *(const float4*)(Wout + (sub << 2));
                float p = y0 * w4.x + y1 * w4.y + y2 * w4.z + y3 * w4.w;
                p += __shfl_xor(p, 1, 64);
                p += __shfl_xor(p, 2, 64);
                p += __shfl_xor(p, 4, 64);
                p += __shfl_xor(p, 8, 64);
                if (sub == 0) out[i] = p + bout[0];
            }
        }
    }
}

extern "C" void kernel_launch(void* const* d_in, const int* in_sizes, int n_in,
                              void* d_out, int out_size, void* d_ws, size_t ws_size,
                              hipStream_t stream) {
    const float* x    = (const float*)d_in[0];
    const void*  ei   = d_in[1];
    const float* Wl1  = (const float*)d_in[2];
    const float* bl1  = (const float*)d_in[3];
    const float* Wr1  = (const float*)d_in[4];
    const float* Wl2  = (const float*)d_in[5];
    const float* bl2  = (const float*)d_in[6];
    const float* Wr2  = (const float*)d_in[7];
    const float* Wl3  = (const float*)d_in[8];
    const float* bl3  = (const float*)d_in[9];
    const float* Wr3  = (const float*)d_in[10];
    const float* Wout = (const float*)d_in[11];
    const float* bout = (const float*)d_in[12];
    float* out = (float*)d_out;

    int       N = in_sizes[0] / D;
    long long E = (long long)in_sizes[1] / 2;
    int ncb = (N + CB_NODES - 1) >> CB_SHIFT;   // <= MAXCB for N <= 131072

    // workspace layout (B1=R/h buffer, B2=P buffer; ebuf aliases B2)
    char* ws = (char*)d_ws;
    size_t off = 256;
    int* ccount = (int*)(ws + off); off += 512;
    int* cbase  = (int*)(ws + off); off += 1024;
    int* ccur   = (int*)(ws + off); off += 512;
    int* rowptr = (int*)(ws + off); off += (((size_t)(N + 1) * 4 + 255) / 256) * 256;
    int* adj    = (int*)(ws + off); off += (((size_t)E * 4 + 255) / 256) * 256;
    float* B1 = (float*)(ws + off); off += (size_t)N * D * 4;
    float* B2 = (float*)(ws + off);
    unsigned* ebuf = (unsigned*)B2;  // consumed by finefill before gemm1 writes P

    // ---- CSR build via two-level counting sort (once; graph layer-invariant) ----
    hipMemsetAsync(ccount, 0, 512, stream);
    chist_kernel<<<256, 256, 0, stream>>>(ei, E, ccount, ncb);
    cscan_kernel<<<1, 128, 0, stream>>>(ccount, cbase, ccur, rowptr, ncb, N, (int)E);
    int sgrid = (int)((E + CHUNK - 1) / CHUNK);
    scatter_kernel<<<sgrid, 256, 0, stream>>>(ei, E, ccur, ebuf, ncb);
    finefill_kernel<<<ncb, 256, 0, stream>>>(ebuf, cbase, rowptr, adj, N);

    int ggrid = (N + 127) / 128;

    // ---- layer 1: P=x@Wl1^T -> B2, R=x@Wr1^T+bl1 -> B1; h1 = leaky(meanP+R) -> B1
    gemm_kernel<<<ggrid, 256, 0, stream>>>(x, Wl1, Wr1, bl1, B2, B1, N);
    agg2_kernel<<<4096, 256, 0, stream>>>(B2, B1, rowptr, adj, Wout, bout, B1, out, N, 0);
    // ---- layer 2: h=B1 (R in-place), P -> B2
    gemm_kernel<<<ggrid, 256, 0, stream>>>(B1, Wl2, Wr2, bl2, B2, B1, N);
    agg2_kernel<<<4096, 256, 0, stream>>>(B2, B1, rowptr, adj, Wout, bout, B1, out, N, 0);
    // ---- layer 3 + fused head
    gemm_kernel<<<ggrid, 256, 0, stream>>>(B1, Wl3, Wr3, bl3, B2, B1, N);
    agg2_kernel<<<4096, 256, 0, stream>>>(B2, B1, rowptr, adj, Wout, bout, B1, out, N, 1);
}

// Round 11
// 373.584 us; speedup vs baseline: 2.6416x; 1.2265x over previous
//
#include <hip/hip_runtime.h>
#include <hip/hip_fp16.h>

#define D 64
#define NEG_SLOPE 0.01f
#define CB_SHIFT 9           // 512 nodes per coarse bucket
#define CB_NODES 512
#define MAXCB 256            // supports N <= 131072
#define CHUNK 8192           // edges per scatter block
#define SADJ_CAP 10240       // LDS adj stage (40 KB); mean bucket 8192, +22 sigma
#define SA_STRIDE 132        // 128 nodes + 4 pad (k-major tile)  [R5-proven]
#define SW2_STRIDE 132       // 128 ch + 4 pad (k-major, Wl|Wr concat)

// ---------------------------------------------------------------------------
// Edge dtype detection, inline per wave: if all odd int32 words of the first
// 128 are zero, the buffer is int64 (little-endian high words).
// ---------------------------------------------------------------------------
__device__ __forceinline__ int detect64(const void* __restrict__ ei) {
    int lane = threadIdx.x & 63;
    int v = ((const int*)ei)[2 * lane + 1];
    return (__ballot(v != 0) == 0ULL) ? 1 : 0;
}

__device__ __forceinline__ int edge_at(const void* __restrict__ ei, long long idx, int is64) {
    if (is64) return (int)((const long long*)ei)[idx];
    return ((const int*)ei)[idx];
}

// ---------------------------------------------------------------------------
// Coarse histogram: per-block LDS hist of dst>>9, <=256 global atomics/block.
// ---------------------------------------------------------------------------
__global__ __launch_bounds__(256) void chist_kernel(
        const void* __restrict__ ei, long long E,
        int* __restrict__ ccount, int ncb) {
    __shared__ int hist[MAXCB];
    int t = threadIdx.x;
    hist[t] = 0;
    int is64 = detect64(ei);
    __syncthreads();
    long long tid = (long long)blockIdx.x * blockDim.x + t;
    long long nt = (long long)gridDim.x * blockDim.x;
    for (long long e = tid; e < E; e += nt) {
        int d = edge_at(ei, E + e, is64);
        atomicAdd(&hist[d >> CB_SHIFT], 1);
    }
    __syncthreads();
    if (t < ncb && hist[t]) atomicAdd(&ccount[t], hist[t]);
}

// parallel exclusive scan of <=256 bucket counts (one block, 256 threads)
__global__ void cscan_kernel(const int* __restrict__ ccount, int* __restrict__ cbase,
                             int* __restrict__ ccur, int* __restrict__ rowptr,
                             int ncb, int N, int E) {
    __shared__ int wsum[4];
    int t = threadIdx.x;           // 256 threads
    int v = (t < ncb) ? ccount[t] : 0;
    int lane = t & 63, w = t >> 6;
    int inc = v;
    for (int off = 1; off < 64; off <<= 1) {
        int u = __shfl_up(inc, off, 64);
        if (lane >= off) inc += u;
    }
    if (lane == 63) wsum[w] = inc;
    __syncthreads();
    int wof = 0;
    for (int i = 0; i < w; ++i) wof += wsum[i];
    int ex = wof + inc - v;
    if (t < ncb) { cbase[t] = ex; ccur[t] = ex; }
    if (t == 0) {
        cbase[ncb] = wsum[0] + wsum[1] + wsum[2] + wsum[3];
        rowptr[N] = E;
    }
}

// ---------------------------------------------------------------------------
// Coarse scatter: LDS-sort an 8192-edge chunk into coarse-bucket order,
// reserve one contiguous global run per (block,bucket), flush packed
// (src<<9 | dstLocal) words in coalesced runs. Block scan replaces the old
// serial t==0 prefix loop.
// ---------------------------------------------------------------------------
__global__ __launch_bounds__(256) void scatter_kernel(
        const void* __restrict__ ei, long long E,
        int* __restrict__ ccur, unsigned* __restrict__ ebuf, int ncb) {
    __shared__ int hist[MAXCB];
    __shared__ int lofs[MAXCB];
    __shared__ int gbase[MAXCB];
    __shared__ int cur[MAXCB];
    __shared__ int swsum[4];
    __shared__ unsigned spk[CHUNK];
    __shared__ unsigned char sbk[CHUNK];
    int t = threadIdx.x;
    hist[t] = 0;
    int is64 = detect64(ei);
    __syncthreads();
    long long start = (long long)blockIdx.x * CHUNK;
    int ccnt = (int)min((long long)CHUNK, E - start);

    for (int i = t; i < ccnt; i += 256) {
        int d = edge_at(ei, E + start + i, is64);
        atomicAdd(&hist[d >> CB_SHIFT], 1);
    }
    __syncthreads();
    {   // block exclusive scan of hist[256] -> lofs
        int v = hist[t];
        int lane = t & 63, w = t >> 6;
        int inc = v;
        for (int off = 1; off < 64; off <<= 1) {
            int u = __shfl_up(inc, off, 64);
            if (lane >= off) inc += u;
        }
        if (lane == 63) swsum[w] = inc;
        __syncthreads();
        int wof = 0;
        for (int i = 0; i < w; ++i) wof += swsum[i];
        lofs[t] = wof + inc - v;
    }
    if (t < ncb && hist[t]) gbase[t] = atomicAdd(&ccur[t], hist[t]);
    __syncthreads();
    cur[t] = lofs[t];
    __syncthreads();

    for (int i = t; i < ccnt; i += 256) {
        int s = edge_at(ei, start + i, is64);
        int d = edge_at(ei, E + start + i, is64);
        int b = d >> CB_SHIFT;
        int slot = atomicAdd(&cur[b], 1);
        spk[slot] = ((unsigned)s << CB_SHIFT) | (unsigned)(d & (CB_NODES - 1));
        sbk[slot] = (unsigned char)b;
    }
    __syncthreads();

    for (int i = t; i < ccnt; i += 256) {
        int b = sbk[i];
        ebuf[gbase[b] + (i - lofs[b])] = spk[i];
    }
}

// ---------------------------------------------------------------------------
// Fine fill: one block per coarse bucket (196 blocks now); per-node count +
// scan -> rowptr; LDS ticket placement; coalesced flush.
// ---------------------------------------------------------------------------
__global__ __launch_bounds__(256) void finefill_kernel(
        const unsigned* __restrict__ ebuf, const int* __restrict__ cbase,
        int* __restrict__ rowptr, int* __restrict__ adj, int N) {
    __shared__ int cnt[CB_NODES];
    __shared__ int cur[CB_NODES];
    __shared__ int wpart[4];
    __shared__ int sAdj[SADJ_CAP];
    int t = threadIdx.x;
    int b = blockIdx.x;
    int e0 = cbase[b], e1 = cbase[b + 1];
    int len = e1 - e0;
    int nb = b << CB_SHIFT;

    cnt[2 * t] = 0; cnt[2 * t + 1] = 0;
    __syncthreads();
    for (int i = t; i < len; i += 256) {
        unsigned p = ebuf[e0 + i];
        atomicAdd(&cnt[p & (CB_NODES - 1)], 1);
    }
    __syncthreads();

    // block exclusive scan of cnt[512]: 2 per thread + wave scan + partials
    int c0 = cnt[2 * t], c1 = cnt[2 * t + 1];
    int s = c0 + c1;
    int lane = t & 63, wv = t >> 6;
    int inc = s;
    for (int off = 1; off < 64; off <<= 1) {
        int u = __shfl_up(inc, off, 64);
        if (lane >= off) inc += u;
    }
    if (lane == 63) wpart[wv] = inc;
    __syncthreads();
    int wof = 0;
    for (int w = 0; w < wv; ++w) wof += wpart[w];
    int ex = wof + inc - s;
    cur[2 * t] = ex; cur[2 * t + 1] = ex + c0;
    {
        int g = nb + 2 * t;
        if (g < N)     rowptr[g]     = e0 + ex;
        if (g + 1 < N) rowptr[g + 1] = e0 + ex + c0;
    }
    __syncthreads();

    int big = (len > SADJ_CAP);
    for (int i = t; i < len; i += 256) {
        unsigned p = ebuf[e0 + i];
        int dl = (int)(p & (CB_NODES - 1));
        int src = (int)(p >> CB_SHIFT);
        int pos = atomicAdd(&cur[dl], 1);
        if (big) adj[e0 + pos] = src;
        else     sAdj[pos] = src;
    }
    __syncthreads();
    if (!big) {
        for (int i = t; i < len; i += 256) adj[e0 + i] = sAdj[i];
    }
}

// ---------------------------------------------------------------------------
// R5-proven k-major staging: 128-node x 64-k tile TRANSPOSED into LDS.
// ---------------------------------------------------------------------------
__device__ __forceinline__ void stage_tile_T(float* __restrict__ sA,
        const float* __restrict__ g, int node_base, int N, int t) {
    int nq = t >> 4;   // 0..15
    int kq = t & 15;   // 0..15
#pragma unroll
    for (int p = 0; p < 8; ++p) {
        int node = p * 16 + nq;
        int gn = node_base + node;
        if (gn >= N) gn = N - 1;   // pad rows: garbage ok, stores masked
        const float4 v = *(const float4*)(g + (size_t)gn * D + (kq << 2));
        sA[(kq * 4 + 0) * SA_STRIDE + node] = v.x;
        sA[(kq * 4 + 1) * SA_STRIDE + node] = v.y;
        sA[(kq * 4 + 2) * SA_STRIDE + node] = v.z;
        sA[(kq * 4 + 3) * SA_STRIDE + node] = v.w;
    }
}

// ---------------------------------------------------------------------------
// gemm_kernel: per layer, ONE pass over h computes BOTH
//   P = h @ Wl^T          (fp16: consumed ONLY by the mean-gather)
//   R = h @ Wr^T + bl     (fp32, written in place over h)
// SAGE linearity: mean(x_j)@Wl^T == mean(x_j@Wl^T). Thread tile 8n x 8c.
// ---------------------------------------------------------------------------
__global__ __launch_bounds__(256) void gemm_kernel(
        const float* __restrict__ h, const float* __restrict__ Wl,
        const float* __restrict__ Wr, const float* __restrict__ bl,
        __half* __restrict__ P, float* __restrict__ R, int N) {
    __shared__ float sA[64 * SA_STRIDE];
    __shared__ float sW[64 * SW2_STRIDE];
    int t = threadIdx.x;
    int node_base = blockIdx.x * 128;

    stage_tile_T(sA, h, node_base, N, t);
    {   // stage Wl -> cols 0..63, Wr -> cols 64..127 (k-major)
        int cq = t >> 4, kq = t & 15;
#pragma unroll
        for (int p = 0; p < 4; ++p) {
            int c = p * 16 + cq;
            const float4 vl = *(const float4*)(Wl + c * D + (kq << 2));
            sW[(kq * 4 + 0) * SW2_STRIDE + c] = vl.x;
            sW[(kq * 4 + 1) * SW2_STRIDE + c] = vl.y;
            sW[(kq * 4 + 2) * SW2_STRIDE + c] = vl.z;
            sW[(kq * 4 + 3) * SW2_STRIDE + c] = vl.w;
            const float4 vr = *(const float4*)(Wr + c * D + (kq << 2));
            sW[(kq * 4 + 0) * SW2_STRIDE + 64 + c] = vr.x;
            sW[(kq * 4 + 1) * SW2_STRIDE + 64 + c] = vr.y;
            sW[(kq * 4 + 2) * SW2_STRIDE + 64 + c] = vr.z;
            sW[(kq * 4 + 3) * SW2_STRIDE + 64 + c] = vr.w;
        }
    }
    __syncthreads();

    int ng = t >> 4;   // node group: 8 nodes
    int cg = t & 15;   // ch group: 8 ch; cg<8 -> P, cg>=8 -> R
    float acc[8][8];
#pragma unroll
    for (int i = 0; i < 8; ++i)
#pragma unroll
        for (int j = 0; j < 8; ++j) acc[i][j] = 0.f;

#pragma unroll 2
    for (int k = 0; k < 64; ++k) {
        const float4 qa0 = *(const float4*)&sA[k * SA_STRIDE + ng * 8];
        const float4 qa1 = *(const float4*)&sA[k * SA_STRIDE + ng * 8 + 4];
        const float4 qw0 = *(const float4*)&sW[k * SW2_STRIDE + cg * 8];
        const float4 qw1 = *(const float4*)&sW[k * SW2_STRIDE + cg * 8 + 4];
        float av[8] = {qa0.x, qa0.y, qa0.z, qa0.w, qa1.x, qa1.y, qa1.z, qa1.w};
        float wv[8] = {qw0.x, qw0.y, qw0.z, qw0.w, qw1.x, qw1.y, qw1.z, qw1.w};
#pragma unroll
        for (int i = 0; i < 8; ++i)
#pragma unroll
            for (int j = 0; j < 8; ++j)
                acc[i][j] = __builtin_fmaf(av[i], wv[j], acc[i][j]);
    }

    if (cg < 8) {
        int hc0 = cg * 4;   // half2 slot base (channels cg*8..+7)
#pragma unroll
        for (int i = 0; i < 8; ++i) {
            int gn = node_base + ng * 8 + i;
            if (gn < N) {
                __half2* prow = (__half2*)(P + (size_t)gn * D) + hc0;
                prow[0] = __floats2half2_rn(acc[i][0], acc[i][1]);
                prow[1] = __floats2half2_rn(acc[i][2], acc[i][3]);
                prow[2] = __floats2half2_rn(acc[i][4], acc[i][5]);
                prow[3] = __floats2half2_rn(acc[i][6], acc[i][7]);
            }
        }
    } else {
        int c0 = (cg - 8) * 8;
        const float4 b0 = *(const float4*)&bl[c0];
        const float4 b1 = *(const float4*)&bl[c0 + 4];
#pragma unroll
        for (int i = 0; i < 8; ++i) {
            int gn = node_base + ng * 8 + i;
            if (gn < N) {
                *(float4*)(R + (size_t)gn * D + c0) =
                    make_float4(acc[i][0] + b0.x, acc[i][1] + b0.y,
                                acc[i][2] + b0.z, acc[i][3] + b0.w);
                *(float4*)(R + (size_t)gn * D + c0 + 4) =
                    make_float4(acc[i][4] + b1.x, acc[i][5] + b1.y,
                                acc[i][6] + b1.z, acc[i][7] + b1.w);
            }
        }
    }
}

// ---------------------------------------------------------------------------
// agg2: gather-mean over fp16 P (128 B/row: 8 lanes x float4 = 8 halves,
// 8 rows in flight per load instr). Epilogue h_next = leaky(meanP + R)
// in fp32, in place over R. final_flag: fused head.
// ---------------------------------------------------------------------------
__global__ __launch_bounds__(256) void agg2_kernel(
        const __half* __restrict__ P, const float* __restrict__ R,
        const int* __restrict__ rowptr, const int* __restrict__ adj,
        const float* __restrict__ Wout, const float* __restrict__ bout,
        float* __restrict__ hout, float* __restrict__ out,
        int N, int final_flag) {
    int lane = threadIdx.x & 63;
    int sub = lane & 7;       // float4 slot (8 halves = channels sub*8..+7)
    int grp = lane >> 3;      // one of 8 concurrent rows
    int wid = blockIdx.x * (blockDim.x >> 6) + (threadIdx.x >> 6);
    int nw = gridDim.x * (blockDim.x >> 6);

    for (int i = wid; i < N; i += nw) {
        int b0 = rowptr[i], b1 = rowptr[i + 1];
        float a0 = 0.f, a1 = 0.f, a2 = 0.f, a3 = 0.f;
        float a4 = 0.f, a5 = 0.f, a6 = 0.f, a7 = 0.f;
        for (int base = b0; base < b1; base += 64) {
            int idx = base + lane;
            int sl = (idx < b1) ? adj[idx] : 0;   // coalesced adj chunk
            int cnt = min(64, b1 - base);
            int nq = (cnt + 7) >> 3;
#pragma unroll 4
            for (int t = 0; t < nq; ++t) {
                int j = (t << 3) + grp;
                int s = __shfl(sl, j, 64);
                if (j < cnt) {
                    union { float4 f4; __half2 h2[4]; } u;
                    u.f4 = *(const float4*)(P + (size_t)s * D + (sub << 3));
                    float2 v0 = __half22float2(u.h2[0]);
                    float2 v1 = __half22float2(u.h2[1]);
                    float2 v2 = __half22float2(u.h2[2]);
                    float2 v3 = __half22float2(u.h2[3]);
                    a0 += v0.x; a1 += v0.y; a2 += v1.x; a3 += v1.y;
                    a4 += v2.x; a5 += v2.y; a6 += v3.x; a7 += v3.y;
                }
            }
        }
#pragma unroll
        for (int o = 8; o <= 32; o <<= 1) {
            a0 += __shfl_xor(a0, o, 64); a1 += __shfl_xor(a1, o, 64);
            a2 += __shfl_xor(a2, o, 64); a3 += __shfl_xor(a3, o, 64);
            a4 += __shfl_xor(a4, o, 64); a5 += __shfl_xor(a5, o, 64);
            a6 += __shfl_xor(a6, o, 64); a7 += __shfl_xor(a7, o, 64);
        }
        if (grp == 0) {
            float inv = 1.0f / fmaxf((float)(b1 - b0), 1.0f);
            int c0 = sub << 3;
            const float4 r0 = *(const float4*)(R + (size_t)i * D + c0);
            const float4 r1 = *(const float4*)(R + (size_t)i * D + c0 + 4);
            float y0 = a0 * inv + r0.x; y0 = (y0 >= 0.f) ? y0 : NEG_SLOPE * y0;
            float y1 = a1 * inv + r0.y; y1 = (y1 >= 0.f) ? y1 : NEG_SLOPE * y1;
            float y2 = a2 * inv + r0.z; y2 = (y2 >= 0.f) ? y2 : NEG_SLOPE * y2;
            float y3 = a3 * inv + r0.w; y3 = (y3 >= 0.f) ? y3 : NEG_SLOPE * y3;
            float y4 = a4 * inv + r1.x; y4 = (y4 >= 0.f) ? y4 : NEG_SLOPE * y4;
            float y5 = a5 * inv + r1.y; y5 = (y5 >= 0.f) ? y5 : NEG_SLOPE * y5;
            float y6 = a6 * inv + r1.z; y6 = (y6 >= 0.f) ? y6 : NEG_SLOPE * y6;
            float y7 = a7 * inv + r1.w; y7 = (y7 >= 0.f) ? y7 : NEG_SLOPE * y7;
            if (!final_flag) {
                *(float4*)(hout + (size_t)i * D + c0) = make_float4(y0, y1, y2, y3);
                *(float4*)(hout + (size_t)i * D + c0 + 4) = make_float4(y4, y5, y6, y7);
            } else {
                const float4 w0 = *(const float4*)(Wout + c0);
                const float4 w1 = *(const float4*)(Wout + c0 + 4);
                float p = y0 * w0.x + y1 * w0.y + y2 * w0.z + y3 * w0.w
                        + y4 * w1.x + y5 * w1.y + y6 * w1.z + y7 * w1.w;
                p += __shfl_xor(p, 1, 64);
                p += __shfl_xor(p, 2, 64);
                p += __shfl_xor(p, 4, 64);
                if (sub == 0) out[i] = p + bout[0];
            }
        }
    }
}

extern "C" void kernel_launch(void* const* d_in, const int* in_sizes, int n_in,
                              void* d_out, int out_size, void* d_ws, size_t ws_size,
                              hipStream_t stream) {
    const float* x    = (const float*)d_in[0];
    const void*  ei   = d_in[1];
    const float* Wl1  = (const float*)d_in[2];
    const float* bl1  = (const float*)d_in[3];
    const float* Wr1  = (const float*)d_in[4];
    const float* Wl2  = (const float*)d_in[5];
    const float* bl2  = (const float*)d_in[6];
    const float* Wr2  = (const float*)d_in[7];
    const float* Wl3  = (const float*)d_in[8];
    const float* bl3  = (const float*)d_in[9];
    const float* Wr3  = (const float*)d_in[10];
    const float* Wout = (const float*)d_in[11];
    const float* bout = (const float*)d_in[12];
    float* out = (float*)d_out;

    int       N = in_sizes[0] / D;
    long long E = (long long)in_sizes[1] / 2;
    int ncb = (N + CB_NODES - 1) >> CB_SHIFT;   // <= 256 for N <= 131072

    // workspace layout (B1 = R/h fp32; B2 = P fp16, also aliases ebuf)
    char* ws = (char*)d_ws;
    size_t off = 256;
    int* ccount = (int*)(ws + off); off += 1024;   // 256 ints
    int* cbase  = (int*)(ws + off); off += 1280;   // 257 ints
    int* ccur   = (int*)(ws + off); off += 1024;   // 256 ints
    int* rowptr = (int*)(ws + off); off += (((size_t)(N + 1) * 4 + 255) / 256) * 256;
    int* adj    = (int*)(ws + off); off += (((size_t)E * 4 + 255) / 256) * 256;
    float* B1 = (float*)(ws + off); off += (size_t)N * D * 4;
    __half* B2h = (__half*)(ws + off);
    unsigned* ebuf = (unsigned*)B2h;  // consumed by finefill before gemm1 writes P

    // ---- CSR build via two-level counting sort (once; graph layer-invariant) ----
    hipMemsetAsync(ccount, 0, 1024, stream);
    chist_kernel<<<256, 256, 0, stream>>>(ei, E, ccount, ncb);
    cscan_kernel<<<1, 256, 0, stream>>>(ccount, cbase, ccur, rowptr, ncb, N, (int)E);
    int sgrid = (int)((E + CHUNK - 1) / CHUNK);
    scatter_kernel<<<sgrid, 256, 0, stream>>>(ei, E, ccur, ebuf, ncb);
    finefill_kernel<<<ncb, 256, 0, stream>>>(ebuf, cbase, rowptr, adj, N);

    int ggrid = (N + 127) / 128;

    // ---- layer 1 ----
    gemm_kernel<<<ggrid, 256, 0, stream>>>(x, Wl1, Wr1, bl1, B2h, B1, N);
    agg2_kernel<<<4096, 256, 0, stream>>>(B2h, B1, rowptr, adj, Wout, bout, B1, out, N, 0);
    // ---- layer 2 ----
    gemm_kernel<<<ggrid, 256, 0, stream>>>(B1, Wl2, Wr2, bl2, B2h, B1, N);
    agg2_kernel<<<4096, 256, 0, stream>>>(B2h, B1, rowptr, adj, Wout, bout, B1, out, N, 0);
    // ---- layer 3 + fused head ----
    gemm_kernel<<<ggrid, 256, 0, stream>>>(B1, Wl3, Wr3, bl3, B2h, B1, N);
    agg2_kernel<<<4096, 256, 0, stream>>>(B2h, B1, rowptr, adj, Wout, bout, B1, out, N, 1);
}

// Round 12
// 340.233 us; speedup vs baseline: 2.9005x; 1.0980x over previous
//
#include <hip/hip_runtime.h>
#include <hip/hip_fp16.h>

#define D 64
#define NEG_SLOPE 0.01f
#define CB_SHIFT 9           // 512 nodes per coarse bucket
#define CB_NODES 512
#define MAXCB 256            // supports N <= 131072
#define CHUNK 8192           // edges per scatter block
#define BCAP 10240           // fixed bucket slab capacity (mean 8163, +23 sigma)
#define SADJ_CAP 10240       // LDS adj stage (40 KB)
#define SA_STRIDE 132        // 128 nodes + 4 pad (k-major tile)  [R5-proven]
#define SW2_STRIDE 132       // 128 ch + 4 pad (k-major, Wl|Wr concat)

// ---------------------------------------------------------------------------
// Edge dtype detection, inline per wave: if all odd int32 words of the first
// 128 are zero, the buffer is int64 (little-endian high words).
// ---------------------------------------------------------------------------
__device__ __forceinline__ int detect64(const void* __restrict__ ei) {
    int lane = threadIdx.x & 63;
    int v = ((const int*)ei)[2 * lane + 1];
    return (__ballot(v != 0) == 0ULL) ? 1 : 0;
}

__device__ __forceinline__ int edge_at(const void* __restrict__ ei, long long idx, int is64) {
    if (is64) return (int)((const long long*)ei)[idx];
    return ((const int*)ei)[idx];
}

// ---------------------------------------------------------------------------
// Coarse scatter (single full-E pass; no pre-count needed): LDS-sort an
// 8192-edge chunk into coarse-bucket order, reserve a contiguous run in the
// bucket's fixed slab via one atomic per (block,bucket), flush packed
// (src<<9 | dstLocal) words in coalesced runs.
// ---------------------------------------------------------------------------
__global__ __launch_bounds__(256) void scatter_kernel(
        const void* __restrict__ ei, long long E,
        int* __restrict__ bcursor, unsigned* __restrict__ ebuf, int ncb) {
    __shared__ int hist[MAXCB];
    __shared__ int lofs[MAXCB];
    __shared__ int gbase[MAXCB];
    __shared__ int cur[MAXCB];
    __shared__ int swsum[4];
    __shared__ unsigned spk[CHUNK];
    __shared__ unsigned char sbk[CHUNK];
    int t = threadIdx.x;
    hist[t] = 0;
    int is64 = detect64(ei);
    __syncthreads();
    long long start = (long long)blockIdx.x * CHUNK;
    int ccnt = (int)min((long long)CHUNK, E - start);

    for (int i = t; i < ccnt; i += 256) {
        int d = edge_at(ei, E + start + i, is64);
        atomicAdd(&hist[d >> CB_SHIFT], 1);
    }
    __syncthreads();
    {   // block exclusive scan of hist[256] -> lofs
        int v = hist[t];
        int lane = t & 63, w = t >> 6;
        int inc = v;
        for (int off = 1; off < 64; off <<= 1) {
            int u = __shfl_up(inc, off, 64);
            if (lane >= off) inc += u;
        }
        if (lane == 63) swsum[w] = inc;
        __syncthreads();
        int wof = 0;
        for (int i = 0; i < w; ++i) wof += swsum[i];
        lofs[t] = wof + inc - v;
    }
    if (t < ncb && hist[t]) gbase[t] = atomicAdd(&bcursor[t], hist[t]);
    __syncthreads();
    cur[t] = lofs[t];
    __syncthreads();

    for (int i = t; i < ccnt; i += 256) {
        int s = edge_at(ei, start + i, is64);
        int d = edge_at(ei, E + start + i, is64);
        int b = d >> CB_SHIFT;
        int slot = atomicAdd(&cur[b], 1);
        spk[slot] = ((unsigned)s << CB_SHIFT) | (unsigned)(d & (CB_NODES - 1));
        sbk[slot] = (unsigned char)b;
    }
    __syncthreads();

    for (int i = t; i < ccnt; i += 256) {
        int b = sbk[i];
        int dst = gbase[b] + (i - lofs[b]);
        if (dst < BCAP) ebuf[(size_t)b * BCAP + dst] = spk[i];
    }
}

// ---------------------------------------------------------------------------
// Fine fill: one block per coarse bucket. Global offset recovered by block-
// scanning the final bucket counts (<=256 ints). Per-node count + scan ->
// rowptr; LDS ticket placement; coalesced flush.
// ---------------------------------------------------------------------------
__global__ __launch_bounds__(256) void finefill_kernel(
        const unsigned* __restrict__ ebuf, const int* __restrict__ bcount,
        int* __restrict__ rowptr, int* __restrict__ adj, int N, int ncb) {
    __shared__ int cnt[CB_NODES];
    __shared__ int cur[CB_NODES];
    __shared__ int wpart[4];
    __shared__ int wsum4[4];
    __shared__ int se0;
    __shared__ int sAdj[SADJ_CAP];
    int t = threadIdx.x;
    int b = blockIdx.x;

    // prefix over bucket counts -> e0 for this block; rowptr[N] from block 0
    {
        int v = (t < ncb) ? min(bcount[t], BCAP) : 0;
        int lane = t & 63, w = t >> 6;
        int inc = v;
        for (int off = 1; off < 64; off <<= 1) {
            int u = __shfl_up(inc, off, 64);
            if (lane >= off) inc += u;
        }
        if (lane == 63) wsum4[w] = inc;
        __syncthreads();
        int wof = 0;
        for (int iw = 0; iw < w; ++iw) wof += wsum4[iw];
        int ex = wof + inc - v;
        if (t == b) se0 = ex;
        if (b == 0 && t == 0)
            rowptr[N] = wsum4[0] + wsum4[1] + wsum4[2] + wsum4[3];
    }
    __syncthreads();
    int e0 = se0;
    int len = min(bcount[b], BCAP);
    int nb = b << CB_SHIFT;
    const unsigned* slab = ebuf + (size_t)b * BCAP;

    cnt[2 * t] = 0; cnt[2 * t + 1] = 0;
    __syncthreads();
    for (int i = t; i < len; i += 256) {
        unsigned p = slab[i];
        atomicAdd(&cnt[p & (CB_NODES - 1)], 1);
    }
    __syncthreads();

    // block exclusive scan of cnt[512]: 2 per thread + wave scan + partials
    int c0 = cnt[2 * t], c1 = cnt[2 * t + 1];
    int s = c0 + c1;
    int lane = t & 63, wv = t >> 6;
    int inc = s;
    for (int off = 1; off < 64; off <<= 1) {
        int u = __shfl_up(inc, off, 64);
        if (lane >= off) inc += u;
    }
    if (lane == 63) wpart[wv] = inc;
    __syncthreads();
    int wof = 0;
    for (int w = 0; w < wv; ++w) wof += wpart[w];
    int ex = wof + inc - s;
    cur[2 * t] = ex; cur[2 * t + 1] = ex + c0;
    {
        int g = nb + 2 * t;
        if (g < N)     rowptr[g]     = e0 + ex;
        if (g + 1 < N) rowptr[g + 1] = e0 + ex + c0;
    }
    __syncthreads();

    int big = (len > SADJ_CAP);
    for (int i = t; i < len; i += 256) {
        unsigned p = slab[i];
        int dl = (int)(p & (CB_NODES - 1));
        int src = (int)(p >> CB_SHIFT);
        int pos = atomicAdd(&cur[dl], 1);
        if (big) adj[e0 + pos] = src;
        else     sAdj[pos] = src;
    }
    __syncthreads();
    if (!big) {
        for (int i = t; i < len; i += 256) adj[e0 + i] = sAdj[i];
    }
}

// ---------------------------------------------------------------------------
// R5-proven k-major staging: 128-node x 64-k tile TRANSPOSED into LDS.
// ---------------------------------------------------------------------------
__device__ __forceinline__ void stage_tile_T(float* __restrict__ sA,
        const float* __restrict__ g, int node_base, int N, int t) {
    int nq = t >> 4;   // 0..15
    int kq = t & 15;   // 0..15
#pragma unroll
    for (int p = 0; p < 8; ++p) {
        int node = p * 16 + nq;
        int gn = node_base + node;
        if (gn >= N) gn = N - 1;   // pad rows: garbage ok, stores masked
        const float4 v = *(const float4*)(g + (size_t)gn * D + (kq << 2));
        sA[(kq * 4 + 0) * SA_STRIDE + node] = v.x;
        sA[(kq * 4 + 1) * SA_STRIDE + node] = v.y;
        sA[(kq * 4 + 2) * SA_STRIDE + node] = v.z;
        sA[(kq * 4 + 3) * SA_STRIDE + node] = v.w;
    }
}

// ---------------------------------------------------------------------------
// gemm_kernel (R10/R11-proven): per layer, ONE pass over h computes BOTH
//   P = h @ Wl^T          (fp16: consumed ONLY by the mean-gather)
//   R = h @ Wr^T + bl     (fp32, written in place over h)
// SAGE linearity: mean(x_j)@Wl^T == mean(x_j@Wl^T). Thread tile 8n x 8c.
// ---------------------------------------------------------------------------
__global__ __launch_bounds__(256) void gemm_kernel(
        const float* __restrict__ h, const float* __restrict__ Wl,
        const float* __restrict__ Wr, const float* __restrict__ bl,
        __half* __restrict__ P, float* __restrict__ R, int N) {
    __shared__ float sA[64 * SA_STRIDE];
    __shared__ float sW[64 * SW2_STRIDE];
    int t = threadIdx.x;
    int node_base = blockIdx.x * 128;

    stage_tile_T(sA, h, node_base, N, t);
    {   // stage Wl -> cols 0..63, Wr -> cols 64..127 (k-major)
        int cq = t >> 4, kq = t & 15;
#pragma unroll
        for (int p = 0; p < 4; ++p) {
            int c = p * 16 + cq;
            const float4 vl = *(const float4*)(Wl + c * D + (kq << 2));
            sW[(kq * 4 + 0) * SW2_STRIDE + c] = vl.x;
            sW[(kq * 4 + 1) * SW2_STRIDE + c] = vl.y;
            sW[(kq * 4 + 2) * SW2_STRIDE + c] = vl.z;
            sW[(kq * 4 + 3) * SW2_STRIDE + c] = vl.w;
            const float4 vr = *(const float4*)(Wr + c * D + (kq << 2));
            sW[(kq * 4 + 0) * SW2_STRIDE + 64 + c] = vr.x;
            sW[(kq * 4 + 1) * SW2_STRIDE + 64 + c] = vr.y;
            sW[(kq * 4 + 2) * SW2_STRIDE + 64 + c] = vr.z;
            sW[(kq * 4 + 3) * SW2_STRIDE + 64 + c] = vr.w;
        }
    }
    __syncthreads();

    int ng = t >> 4;   // node group: 8 nodes
    int cg = t & 15;   // ch group: 8 ch; cg<8 -> P, cg>=8 -> R
    float acc[8][8];
#pragma unroll
    for (int i = 0; i < 8; ++i)
#pragma unroll
        for (int j = 0; j < 8; ++j) acc[i][j] = 0.f;

#pragma unroll 2
    for (int k = 0; k < 64; ++k) {
        const float4 qa0 = *(const float4*)&sA[k * SA_STRIDE + ng * 8];
        const float4 qa1 = *(const float4*)&sA[k * SA_STRIDE + ng * 8 + 4];
        const float4 qw0 = *(const float4*)&sW[k * SW2_STRIDE + cg * 8];
        const float4 qw1 = *(const float4*)&sW[k * SW2_STRIDE + cg * 8 + 4];
        float av[8] = {qa0.x, qa0.y, qa0.z, qa0.w, qa1.x, qa1.y, qa1.z, qa1.w};
        float wv[8] = {qw0.x, qw0.y, qw0.z, qw0.w, qw1.x, qw1.y, qw1.z, qw1.w};
#pragma unroll
        for (int i = 0; i < 8; ++i)
#pragma unroll
            for (int j = 0; j < 8; ++j)
                acc[i][j] = __builtin_fmaf(av[i], wv[j], acc[i][j]);
    }

    if (cg < 8) {
        int hc0 = cg * 4;   // half2 slot base (channels cg*8..+7)
#pragma unroll
        for (int i = 0; i < 8; ++i) {
            int gn = node_base + ng * 8 + i;
            if (gn < N) {
                __half2* prow = (__half2*)(P + (size_t)gn * D) + hc0;
                prow[0] = __floats2half2_rn(acc[i][0], acc[i][1]);
                prow[1] = __floats2half2_rn(acc[i][2], acc[i][3]);
                prow[2] = __floats2half2_rn(acc[i][4], acc[i][5]);
                prow[3] = __floats2half2_rn(acc[i][6], acc[i][7]);
            }
        }
    } else {
        int c0 = (cg - 8) * 8;
        const float4 b0 = *(const float4*)&bl[c0];
        const float4 b1 = *(const float4*)&bl[c0 + 4];
#pragma unroll
        for (int i = 0; i < 8; ++i) {
            int gn = node_base + ng * 8 + i;
            if (gn < N) {
                *(float4*)(R + (size_t)gn * D + c0) =
                    make_float4(acc[i][0] + b0.x, acc[i][1] + b0.y,
                                acc[i][2] + b0.z, acc[i][3] + b0.w);
                *(float4*)(R + (size_t)gn * D + c0 + 4) =
                    make_float4(acc[i][4] + b1.x, acc[i][5] + b1.y,
                                acc[i][6] + b1.z, acc[i][7] + b1.w);
            }
        }
    }
}

// ---------------------------------------------------------------------------
// agg3: 8-lane group per node. Each lane owns 8 fp16 channels (16 B), so a
// group reads a full 128 B P-row coalesced per edge; accumulation is lane-
// local (NO shuffle broadcast, NO cross-lane reduction, all lanes active in
// the epilogue). Divergence cost = max degree among the wave's 8 groups.
// Epilogue: h_next = leaky(meanP + R) in place over R; final: 3-shfl head.
// ---------------------------------------------------------------------------
__global__ __launch_bounds__(256) void agg3_kernel(
        const __half* __restrict__ P, const float* __restrict__ R,
        const int* __restrict__ rowptr, const int* __restrict__ adj,
        const float* __restrict__ Wout, const float* __restrict__ bout,
        float* __restrict__ hout, float* __restrict__ out,
        int N, int final_flag) {
    int tid = blockIdx.x * blockDim.x + threadIdx.x;
    int i = tid >> 3;          // node owned by this 8-lane group
    int sub = tid & 7;         // channel slot: 8 halves = 16 B
    if (i >= N) return;

    int b0 = rowptr[i], b1 = rowptr[i + 1];
    float a0 = 0.f, a1 = 0.f, a2 = 0.f, a3 = 0.f;
    float a4 = 0.f, a5 = 0.f, a6 = 0.f, a7 = 0.f;
    size_t cofs = (size_t)(sub << 3);

    int e = b0;
    int nfull = (b1 - b0) >> 2;
#pragma unroll 2
    for (int q = 0; q < nfull; ++q) {
        int s0 = adj[e], s1 = adj[e + 1], s2 = adj[e + 2], s3 = adj[e + 3];
        e += 4;
        union { float4 f4; __half2 h2[4]; } u0, u1, u2, u3;
        u0.f4 = *(const float4*)(P + (size_t)s0 * D + cofs);
        u1.f4 = *(const float4*)(P + (size_t)s1 * D + cofs);
        u2.f4 = *(const float4*)(P + (size_t)s2 * D + cofs);
        u3.f4 = *(const float4*)(P + (size_t)s3 * D + cofs);
#define ACC8(u) { \
        float2 v0 = __half22float2(u.h2[0]); float2 v1 = __half22float2(u.h2[1]); \
        float2 v2 = __half22float2(u.h2[2]); float2 v3 = __half22float2(u.h2[3]); \
        a0 += v0.x; a1 += v0.y; a2 += v1.x; a3 += v1.y; \
        a4 += v2.x; a5 += v2.y; a6 += v3.x; a7 += v3.y; }
        ACC8(u0) ACC8(u1) ACC8(u2) ACC8(u3)
    }
    for (; e < b1; ++e) {
        int s = adj[e];
        union { float4 f4; __half2 h2[4]; } u;
        u.f4 = *(const float4*)(P + (size_t)s * D + cofs);
        ACC8(u)
    }
#undef ACC8

    float inv = 1.0f / fmaxf((float)(b1 - b0), 1.0f);
    const float4 r0 = *(const float4*)(R + (size_t)i * D + cofs);
    const float4 r1 = *(const float4*)(R + (size_t)i * D + cofs + 4);
    float y0 = a0 * inv + r0.x; y0 = (y0 >= 0.f) ? y0 : NEG_SLOPE * y0;
    float y1 = a1 * inv + r0.y; y1 = (y1 >= 0.f) ? y1 : NEG_SLOPE * y1;
    float y2 = a2 * inv + r0.z; y2 = (y2 >= 0.f) ? y2 : NEG_SLOPE * y2;
    float y3 = a3 * inv + r0.w; y3 = (y3 >= 0.f) ? y3 : NEG_SLOPE * y3;
    float y4 = a4 * inv + r1.x; y4 = (y4 >= 0.f) ? y4 : NEG_SLOPE * y4;
    float y5 = a5 * inv + r1.y; y5 = (y5 >= 0.f) ? y5 : NEG_SLOPE * y5;
    float y6 = a6 * inv + r1.z; y6 = (y6 >= 0.f) ? y6 : NEG_SLOPE * y6;
    float y7 = a7 * inv + r1.w; y7 = (y7 >= 0.f) ? y7 : NEG_SLOPE * y7;
    if (!final_flag) {
        *(float4*)(hout + (size_t)i * D + cofs) = make_float4(y0, y1, y2, y3);
        *(float4*)(hout + (size_t)i * D + cofs + 4) = make_float4(y4, y5, y6, y7);
    } else {
        const float4 w0 = *(const float4*)(Wout + cofs);
        const float4 w1 = *(const float4*)(Wout + cofs + 4);
        float p = y0 * w0.x + y1 * w0.y + y2 * w0.z + y3 * w0.w
                + y4 * w1.x + y5 * w1.y + y6 * w1.z + y7 * w1.w;
        p += __shfl_xor(p, 1, 64);   // offsets 1,2,4 stay inside the 8-lane group
        p += __shfl_xor(p, 2, 64);
        p += __shfl_xor(p, 4, 64);
        if (sub == 0) out[i] = p + bout[0];
    }
}

extern "C" void kernel_launch(void* const* d_in, const int* in_sizes, int n_in,
                              void* d_out, int out_size, void* d_ws, size_t ws_size,
                              hipStream_t stream) {
    const float* x    = (const float*)d_in[0];
    const void*  ei   = d_in[1];
    const float* Wl1  = (const float*)d_in[2];
    const float* bl1  = (const float*)d_in[3];
    const float* Wr1  = (const float*)d_in[4];
    const float* Wl2  = (const float*)d_in[5];
    const float* bl2  = (const float*)d_in[6];
    const float* Wr2  = (const float*)d_in[7];
    const float* Wl3  = (const float*)d_in[8];
    const float* bl3  = (const float*)d_in[9];
    const float* Wr3  = (const float*)d_in[10];
    const float* Wout = (const float*)d_in[11];
    const float* bout = (const float*)d_in[12];
    float* out = (float*)d_out;

    int       N = in_sizes[0] / D;
    long long E = (long long)in_sizes[1] / 2;
    int ncb = (N + CB_NODES - 1) >> CB_SHIFT;   // <= 256 for N <= 131072

    // workspace layout (B1 = R/h fp32; B2 = P fp16, slab-ebuf aliases B2)
    char* ws = (char*)d_ws;
    size_t off = 256;
    int* bcursor = (int*)(ws + off); off += 1024;   // 256 ints
    int* rowptr = (int*)(ws + off); off += (((size_t)(N + 1) * 4 + 255) / 256) * 256;
    int* adj    = (int*)(ws + off); off += (((size_t)E * 4 + 255) / 256) * 256;
    float* B1 = (float*)(ws + off); off += (size_t)N * D * 4;
    __half* B2h = (__half*)(ws + off);
    unsigned* ebuf = (unsigned*)B2h;  // ncb*BCAP*4 B <= N*D*2 B; consumed pre-gemm1

    // ---- CSR build: scatter into fixed slabs + fine fill (2 kernels) ----
    hipMemsetAsync(bcursor, 0, 1024, stream);
    int sgrid = (int)((E + CHUNK - 1) / CHUNK);
    scatter_kernel<<<sgrid, 256, 0, stream>>>(ei, E, bcursor, ebuf, ncb);
    finefill_kernel<<<ncb, 256, 0, stream>>>(ebuf, bcursor, rowptr, adj, N, ncb);

    int ggrid = (N + 127) / 128;
    int agrid = (N * 8 + 255) / 256;

    // ---- layer 1 ----
    gemm_kernel<<<ggrid, 256, 0, stream>>>(x, Wl1, Wr1, bl1, B2h, B1, N);
    agg3_kernel<<<agrid, 256, 0, stream>>>(B2h, B1, rowptr, adj, Wout, bout, B1, out, N, 0);
    // ---- layer 2 ----
    gemm_kernel<<<ggrid, 256, 0, stream>>>(B1, Wl2, Wr2, bl2, B2h, B1, N);
    agg3_kernel<<<agrid, 256, 0, stream>>>(B2h, B1, rowptr, adj, Wout, bout, B1, out, N, 0);
    // ---- layer 3 + fused head ----
    gemm_kernel<<<ggrid, 256, 0, stream>>>(B1, Wl3, Wr3, bl3, B2h, B1, N);
    agg3_kernel<<<agrid, 256, 0, stream>>>(B2h, B1, rowptr, adj, Wout, bout, B1, out, N, 1);
}

// Round 13
// 310.731 us; speedup vs baseline: 3.1759x; 1.0949x over previous
//
#include <hip/hip_runtime.h>
#include <hip/hip_fp16.h>

#define D 64
#define NEG_SLOPE 0.01f
#define CB_SHIFT 9           // 512 nodes per coarse bucket
#define CB_NODES 512
#define MAXCB 256            // supports N <= 131072
#define CHUNK 8192           // edges per scatter block
#define BCAP 10240           // fixed bucket slab capacity (mean 8163, +23 sigma)
#define SADJ_CAP 10240       // LDS adj stage (40 KB)
#define SA_STRIDE 132        // 128 nodes + 4 pad (k-major tile)  [R5-proven]
#define SW_STRIDE 68         // 64 ch + 4 pad (k-major W tile)    [R8-proven]

// ---------------------------------------------------------------------------
// Shared-memory union: gemm tile (50 KB) vs scatter workspace (45 KB).
// ---------------------------------------------------------------------------
struct GemmSmem {
    float sA[64 * SA_STRIDE];   // 33792 B
    float sW[64 * SW_STRIDE];   // 17408 B
};
struct ScatSmem {
    int hist[MAXCB];
    int lofs[MAXCB];
    int gbase[MAXCB];
    int cur[MAXCB];
    int swsum[4];
    unsigned spk[CHUNK];        // 32 KB
    unsigned char sbk[CHUNK];   // 8 KB
};
union FusedSmem { GemmSmem g; ScatSmem s; };

// ---------------------------------------------------------------------------
// Edge dtype detection, inline per wave: if all odd int32 words of the first
// 128 are zero, the buffer is int64 (little-endian high words).
// ---------------------------------------------------------------------------
__device__ __forceinline__ int detect64(const void* __restrict__ ei) {
    int lane = threadIdx.x & 63;
    int v = ((const int*)ei)[2 * lane + 1];
    return (__ballot(v != 0) == 0ULL) ? 1 : 0;
}

__device__ __forceinline__ int edge_at(const void* __restrict__ ei, long long idx, int is64) {
    if (is64) return (int)((const long long*)ei)[idx];
    return ((const int*)ei)[idx];
}

// ---------------------------------------------------------------------------
// Coarse scatter body (R12-proven): LDS-sort an 8192-edge chunk into coarse-
// bucket order, reserve a contiguous run in the bucket's fixed slab via one
// atomic per (block,bucket), flush packed (src<<9 | dstLocal) words.
// ---------------------------------------------------------------------------
__device__ __forceinline__ void scatter_body(ScatSmem& sm,
        const void* __restrict__ ei, long long E,
        int* __restrict__ bcursor, unsigned* __restrict__ ebuf,
        int ncb, int bid) {
    int t = threadIdx.x;
    sm.hist[t] = 0;
    int is64 = detect64(ei);
    __syncthreads();
    long long start = (long long)bid * CHUNK;
    int ccnt = (int)min((long long)CHUNK, E - start);

    for (int i = t; i < ccnt; i += 256) {
        int d = edge_at(ei, E + start + i, is64);
        atomicAdd(&sm.hist[d >> CB_SHIFT], 1);
    }
    __syncthreads();
    {   // block exclusive scan of hist[256] -> lofs
        int v = sm.hist[t];
        int lane = t & 63, w = t >> 6;
        int inc = v;
        for (int off = 1; off < 64; off <<= 1) {
            int u = __shfl_up(inc, off, 64);
            if (lane >= off) inc += u;
        }
        if (lane == 63) sm.swsum[w] = inc;
        __syncthreads();
        int wof = 0;
        for (int i = 0; i < w; ++i) wof += sm.swsum[i];
        sm.lofs[t] = wof + inc - v;
    }
    if (t < ncb && sm.hist[t]) sm.gbase[t] = atomicAdd(&bcursor[t], sm.hist[t]);
    __syncthreads();
    sm.cur[t] = sm.lofs[t];
    __syncthreads();

    for (int i = t; i < ccnt; i += 256) {
        int s = edge_at(ei, start + i, is64);
        int d = edge_at(ei, E + start + i, is64);
        int b = d >> CB_SHIFT;
        int slot = atomicAdd(&sm.cur[b], 1);
        sm.spk[slot] = ((unsigned)s << CB_SHIFT) | (unsigned)(d & (CB_NODES - 1));
        sm.sbk[slot] = (unsigned char)b;
    }
    __syncthreads();

    for (int i = t; i < ccnt; i += 256) {
        int b = sm.sbk[i];
        int dst = sm.gbase[b] + (i - sm.lofs[b]);
        if (dst < BCAP) ebuf[(size_t)b * BCAP + dst] = sm.spk[i];
    }
}

// ---------------------------------------------------------------------------
// R5-proven k-major staging: 128-node x 64-k tile TRANSPOSED into LDS.
// ---------------------------------------------------------------------------
__device__ __forceinline__ void stage_tile_T(float* __restrict__ sA,
        const float* __restrict__ g, int node_base, int N, int t) {
    int nq = t >> 4;   // 0..15
    int kq = t & 15;   // 0..15
#pragma unroll
    for (int p = 0; p < 8; ++p) {
        int node = p * 16 + nq;
        int gn = node_base + node;
        if (gn >= N) gn = N - 1;   // pad rows: garbage ok, stores masked
        const float4 v = *(const float4*)(g + (size_t)gn * D + (kq << 2));
        sA[(kq * 4 + 0) * SA_STRIDE + node] = v.x;
        sA[(kq * 4 + 1) * SA_STRIDE + node] = v.y;
        sA[(kq * 4 + 2) * SA_STRIDE + node] = v.z;
        sA[(kq * 4 + 3) * SA_STRIDE + node] = v.w;
    }
}

__device__ __forceinline__ void stage_w_T(float* __restrict__ sW,
        const float* __restrict__ W, int t) {
    int cq = t >> 4;
    int kq = t & 15;
#pragma unroll
    for (int p = 0; p < 4; ++p) {
        int c = p * 16 + cq;
        const float4 v = *(const float4*)(W + c * D + (kq << 2));
        sW[(kq * 4 + 0) * SW_STRIDE + c] = v.x;
        sW[(kq * 4 + 1) * SW_STRIDE + c] = v.y;
        sW[(kq * 4 + 2) * SW_STRIDE + c] = v.z;
        sW[(kq * 4 + 3) * SW_STRIDE + c] = v.w;
    }
}

__device__ __forceinline__ void kloop4(float acc[8][4],
        const float* __restrict__ sA, const float* __restrict__ sW,
        int ng, int cg) {
#pragma unroll 4
    for (int k = 0; k < 64; ++k) {
        const float4 qa0 = *(const float4*)&sA[k * SA_STRIDE + ng * 8];
        const float4 qa1 = *(const float4*)&sA[k * SA_STRIDE + ng * 8 + 4];
        const float4 qb  = *(const float4*)&sW[k * SW_STRIDE + cg * 4];
        float av[8] = {qa0.x, qa0.y, qa0.z, qa0.w, qa1.x, qa1.y, qa1.z, qa1.w};
        float bv[4] = {qb.x, qb.y, qb.z, qb.w};
#pragma unroll
        for (int i = 0; i < 8; ++i)
#pragma unroll
            for (int j = 0; j < 4; ++j)
                acc[i][j] = __builtin_fmaf(av[i], bv[j], acc[i][j]);
    }
}

// ---------------------------------------------------------------------------
// gemm body: ONE h-tile staged once; Wl staged (17 KB) -> kloopA -> accP;
// restage Wr -> kloopB -> accR. Every thread owns 8 nodes x 4 ch of BOTH
//   P = h @ Wl^T   (fp16, consumed only by the mean-gather)
//   R = h @ Wr^T + bl  (fp32, in place over h)
// LDS 50 KB -> 3 blocks/CU (vs 67.6 KB/2 before).
// ---------------------------------------------------------------------------
__device__ __forceinline__ void gemm_body(GemmSmem& sm,
        const float* __restrict__ h, const float* __restrict__ Wl,
        const float* __restrict__ Wr, const float* __restrict__ bl,
        __half* __restrict__ P, float* __restrict__ R, int N, int bid) {
    int t = threadIdx.x;
    int node_base = bid * 128;

    stage_tile_T(sm.sA, h, node_base, N, t);
    stage_w_T(sm.sW, Wl, t);
    __syncthreads();

    int ng = t >> 4;   // node group: 8 nodes
    int cg = t & 15;   // channel group: 4 channels
    float accP[8][4], accR[8][4];
#pragma unroll
    for (int i = 0; i < 8; ++i)
#pragma unroll
        for (int j = 0; j < 4; ++j) { accP[i][j] = 0.f; accR[i][j] = 0.f; }

    kloop4(accP, sm.sA, sm.sW, ng, cg);     // pass A: h @ Wl^T
    __syncthreads();
    stage_w_T(sm.sW, Wr, t);                // only the 17 KB W tile restages
    __syncthreads();
    kloop4(accR, sm.sA, sm.sW, ng, cg);     // pass B: h @ Wr^T

    const float4 bq = *(const float4*)&bl[cg * 4];
#pragma unroll
    for (int i = 0; i < 8; ++i) {
        int gn = node_base + ng * 8 + i;
        if (gn < N) {
            __half2* ph = (__half2*)(P + (size_t)gn * D + cg * 4);
            ph[0] = __floats2half2_rn(accP[i][0], accP[i][1]);
            ph[1] = __floats2half2_rn(accP[i][2], accP[i][3]);
            *(float4*)(R + (size_t)gn * D + cg * 4) =
                make_float4(accR[i][0] + bq.x, accR[i][1] + bq.y,
                            accR[i][2] + bq.z, accR[i][3] + bq.w);
        }
    }
}

// ---------------------------------------------------------------------------
// Layer-1 fused launch: scatter blocks first (dispatch immediately), gemm
// blocks fill the machine behind them. Independent work, one kernel.
// ---------------------------------------------------------------------------
__global__ __launch_bounds__(256, 3) void gemm1_scatter_kernel(
        const void* __restrict__ ei, long long E,
        int* __restrict__ bcursor, unsigned* __restrict__ ebuf, int ncb, int sgrid,
        const float* __restrict__ h, const float* __restrict__ Wl,
        const float* __restrict__ Wr, const float* __restrict__ bl,
        __half* __restrict__ P, float* __restrict__ R, int N) {
    __shared__ FusedSmem sm;
    if ((int)blockIdx.x < sgrid) {
        scatter_body(sm.s, ei, E, bcursor, ebuf, ncb, blockIdx.x);
    } else {
        gemm_body(sm.g, h, Wl, Wr, bl, P, R, N, blockIdx.x - sgrid);
    }
}

__global__ __launch_bounds__(256, 3) void gemm_kernel(
        const float* __restrict__ h, const float* __restrict__ Wl,
        const float* __restrict__ Wr, const float* __restrict__ bl,
        __half* __restrict__ P, float* __restrict__ R, int N) {
    __shared__ GemmSmem sm;
    gemm_body(sm, h, Wl, Wr, bl, P, R, N, blockIdx.x);
}

// ---------------------------------------------------------------------------
// Fine fill (R12-proven): one block per coarse bucket. Global offset from a
// block-scan of final bucket counts; per-node count + scan -> rowptr; LDS
// ticket placement; coalesced flush.
// ---------------------------------------------------------------------------
__global__ __launch_bounds__(256) void finefill_kernel(
        const unsigned* __restrict__ ebuf, const int* __restrict__ bcount,
        int* __restrict__ rowptr, int* __restrict__ adj, int N, int ncb) {
    __shared__ int cnt[CB_NODES];
    __shared__ int cur[CB_NODES];
    __shared__ int wpart[4];
    __shared__ int wsum4[4];
    __shared__ int se0;
    __shared__ int sAdj[SADJ_CAP];
    int t = threadIdx.x;
    int b = blockIdx.x;

    {
        int v = (t < ncb) ? min(bcount[t], BCAP) : 0;
        int lane = t & 63, w = t >> 6;
        int inc = v;
        for (int off = 1; off < 64; off <<= 1) {
            int u = __shfl_up(inc, off, 64);
            if (lane >= off) inc += u;
        }
        if (lane == 63) wsum4[w] = inc;
        __syncthreads();
        int wof = 0;
        for (int iw = 0; iw < w; ++iw) wof += wsum4[iw];
        int ex = wof + inc - v;
        if (t == b) se0 = ex;
        if (b == 0 && t == 0)
            rowptr[N] = wsum4[0] + wsum4[1] + wsum4[2] + wsum4[3];
    }
    __syncthreads();
    int e0 = se0;
    int len = min(bcount[b], BCAP);
    int nb = b << CB_SHIFT;
    const unsigned* slab = ebuf + (size_t)b * BCAP;

    cnt[2 * t] = 0; cnt[2 * t + 1] = 0;
    __syncthreads();
    for (int i = t; i < len; i += 256) {
        unsigned p = slab[i];
        atomicAdd(&cnt[p & (CB_NODES - 1)], 1);
    }
    __syncthreads();

    int c0 = cnt[2 * t], c1 = cnt[2 * t + 1];
    int s = c0 + c1;
    int lane = t & 63, wv = t >> 6;
    int inc = s;
    for (int off = 1; off < 64; off <<= 1) {
        int u = __shfl_up(inc, off, 64);
        if (lane >= off) inc += u;
    }
    if (lane == 63) wpart[wv] = inc;
    __syncthreads();
    int wof = 0;
    for (int w = 0; w < wv; ++w) wof += wpart[w];
    int ex = wof + inc - s;
    cur[2 * t] = ex; cur[2 * t + 1] = ex + c0;
    {
        int g = nb + 2 * t;
        if (g < N)     rowptr[g]     = e0 + ex;
        if (g + 1 < N) rowptr[g + 1] = e0 + ex + c0;
    }
    __syncthreads();

    int big = (len > SADJ_CAP);
    for (int i = t; i < len; i += 256) {
        unsigned p = slab[i];
        int dl = (int)(p & (CB_NODES - 1));
        int src = (int)(p >> CB_SHIFT);
        int pos = atomicAdd(&cur[dl], 1);
        if (big) adj[e0 + pos] = src;
        else     sAdj[pos] = src;
    }
    __syncthreads();
    if (!big) {
        for (int i = t; i < len; i += 256) adj[e0 + i] = sAdj[i];
    }
}

// ---------------------------------------------------------------------------
// agg3 (R12-proven): 8-lane group per node, lane owns 8 fp16 channels.
// 128 B coalesced P-row per edge, lane-local accumulation, no reductions.
// Epilogue: h_next = leaky(meanP + R) in place over R; final: 3-shfl head.
// ---------------------------------------------------------------------------
__global__ __launch_bounds__(256) void agg3_kernel(
        const __half* __restrict__ P, const float* __restrict__ R,
        const int* __restrict__ rowptr, const int* __restrict__ adj,
        const float* __restrict__ Wout, const float* __restrict__ bout,
        float* __restrict__ hout, float* __restrict__ out,
        int N, int final_flag) {
    int tid = blockIdx.x * blockDim.x + threadIdx.x;
    int i = tid >> 3;          // node owned by this 8-lane group
    int sub = tid & 7;         // channel slot: 8 halves = 16 B
    if (i >= N) return;

    int b0 = rowptr[i], b1 = rowptr[i + 1];
    float a0 = 0.f, a1 = 0.f, a2 = 0.f, a3 = 0.f;
    float a4 = 0.f, a5 = 0.f, a6 = 0.f, a7 = 0.f;
    size_t cofs = (size_t)(sub << 3);

    int e = b0;
    int nfull = (b1 - b0) >> 2;
#pragma unroll 2
    for (int q = 0; q < nfull; ++q) {
        int s0 = adj[e], s1 = adj[e + 1], s2 = adj[e + 2], s3 = adj[e + 3];
        e += 4;
        union { float4 f4; __half2 h2[4]; } u0, u1, u2, u3;
        u0.f4 = *(const float4*)(P + (size_t)s0 * D + cofs);
        u1.f4 = *(const float4*)(P + (size_t)s1 * D + cofs);
        u2.f4 = *(const float4*)(P + (size_t)s2 * D + cofs);
        u3.f4 = *(const float4*)(P + (size_t)s3 * D + cofs);
#define ACC8(u) { \
        float2 v0 = __half22float2(u.h2[0]); float2 v1 = __half22float2(u.h2[1]); \
        float2 v2 = __half22float2(u.h2[2]); float2 v3 = __half22float2(u.h2[3]); \
        a0 += v0.x; a1 += v0.y; a2 += v1.x; a3 += v1.y; \
        a4 += v2.x; a5 += v2.y; a6 += v3.x; a7 += v3.y; }
        ACC8(u0) ACC8(u1) ACC8(u2) ACC8(u3)
    }
    for (; e < b1; ++e) {
        int s = adj[e];
        union { float4 f4; __half2 h2[4]; } u;
        u.f4 = *(const float4*)(P + (size_t)s * D + cofs);
        ACC8(u)
    }
#undef ACC8

    float inv = 1.0f / fmaxf((float)(b1 - b0), 1.0f);
    const float4 r0 = *(const float4*)(R + (size_t)i * D + cofs);
    const float4 r1 = *(const float4*)(R + (size_t)i * D + cofs + 4);
    float y0 = a0 * inv + r0.x; y0 = (y0 >= 0.f) ? y0 : NEG_SLOPE * y0;
    float y1 = a1 * inv + r0.y; y1 = (y1 >= 0.f) ? y1 : NEG_SLOPE * y1;
    float y2 = a2 * inv + r0.z; y2 = (y2 >= 0.f) ? y2 : NEG_SLOPE * y2;
    float y3 = a3 * inv + r0.w; y3 = (y3 >= 0.f) ? y3 : NEG_SLOPE * y3;
    float y4 = a4 * inv + r1.x; y4 = (y4 >= 0.f) ? y4 : NEG_SLOPE * y4;
    float y5 = a5 * inv + r1.y; y5 = (y5 >= 0.f) ? y5 : NEG_SLOPE * y5;
    float y6 = a6 * inv + r1.z; y6 = (y6 >= 0.f) ? y6 : NEG_SLOPE * y6;
    float y7 = a7 * inv + r1.w; y7 = (y7 >= 0.f) ? y7 : NEG_SLOPE * y7;
    if (!final_flag) {
        *(float4*)(hout + (size_t)i * D + cofs) = make_float4(y0, y1, y2, y3);
        *(float4*)(hout + (size_t)i * D + cofs + 4) = make_float4(y4, y5, y6, y7);
    } else {
        const float4 w0 = *(const float4*)(Wout + cofs);
        const float4 w1 = *(const float4*)(Wout + cofs + 4);
        float p = y0 * w0.x + y1 * w0.y + y2 * w0.z + y3 * w0.w
                + y4 * w1.x + y5 * w1.y + y6 * w1.z + y7 * w1.w;
        p += __shfl_xor(p, 1, 64);   // offsets 1,2,4 stay inside the 8-lane group
        p += __shfl_xor(p, 2, 64);
        p += __shfl_xor(p, 4, 64);
        if (sub == 0) out[i] = p + bout[0];
    }
}

extern "C" void kernel_launch(void* const* d_in, const int* in_sizes, int n_in,
                              void* d_out, int out_size, void* d_ws, size_t ws_size,
                              hipStream_t stream) {
    const float* x    = (const float*)d_in[0];
    const void*  ei   = d_in[1];
    const float* Wl1  = (const float*)d_in[2];
    const float* bl1  = (const float*)d_in[3];
    const float* Wr1  = (const float*)d_in[4];
    const float* Wl2  = (const float*)d_in[5];
    const float* bl2  = (const float*)d_in[6];
    const float* Wr2  = (const float*)d_in[7];
    const float* Wl3  = (const float*)d_in[8];
    const float* bl3  = (const float*)d_in[9];
    const float* Wr3  = (const float*)d_in[10];
    const float* Wout = (const float*)d_in[11];
    const float* bout = (const float*)d_in[12];
    float* out = (float*)d_out;

    int       N = in_sizes[0] / D;
    long long E = (long long)in_sizes[1] / 2;
    int ncb = (N + CB_NODES - 1) >> CB_SHIFT;   // <= 256 for N <= 131072

    // workspace layout. ebuf now has a DEDICATED slab (scatter runs
    // concurrently with gemm1, which writes P) — no aliasing with B2h.
    char* ws = (char*)d_ws;
    size_t off = 256;
    int* bcursor = (int*)(ws + off); off += 1024;   // 256 ints
    int* rowptr = (int*)(ws + off); off += (((size_t)(N + 1) * 4 + 255) / 256) * 256;
    int* adj    = (int*)(ws + off); off += (((size_t)E * 4 + 255) / 256) * 256;
    unsigned* ebuf = (unsigned*)(ws + off); off += (size_t)ncb * BCAP * 4;
    float* B1 = (float*)(ws + off); off += (size_t)N * D * 4;
    __half* B2h = (__half*)(ws + off);

    int sgrid = (int)((E + CHUNK - 1) / CHUNK);
    int ggrid = (N + 127) / 128;
    int agrid = (N * 8 + 255) / 256;

    hipMemsetAsync(bcursor, 0, 1024, stream);

    // ---- layer 1: scatter (CSR) runs CONCURRENTLY with gemm1 ----
    gemm1_scatter_kernel<<<sgrid + ggrid, 256, 0, stream>>>(
        ei, E, bcursor, ebuf, ncb, sgrid,
        x, Wl1, Wr1, bl1, B2h, B1, N);
    finefill_kernel<<<ncb, 256, 0, stream>>>(ebuf, bcursor, rowptr, adj, N, ncb);
    agg3_kernel<<<agrid, 256, 0, stream>>>(B2h, B1, rowptr, adj, Wout, bout, B1, out, N, 0);
    // ---- layer 2 ----
    gemm_kernel<<<ggrid, 256, 0, stream>>>(B1, Wl2, Wr2, bl2, B2h, B1, N);
    agg3_kernel<<<agrid, 256, 0, stream>>>(B2h, B1, rowptr, adj, Wout, bout, B1, out, N, 0);
    // ---- layer 3 + fused head ----
    gemm_kernel<<<ggrid, 256, 0, stream>>>(B1, Wl3, Wr3, bl3, B2h, B1, N);
    agg3_kernel<<<agrid, 256, 0, stream>>>(B2h, B1, rowptr, adj, Wout, bout, B1, out, N, 1);
}